// Round 11
// baseline (506.426 us; speedup 1.0000x reference)
//
#include <hip/hip_runtime.h>

#define NN 50000
#define EE 800000
#define NB_EDGE 3125   // ceil(EE/256)
#define NB_E1   1563   // ceil(EE/512)
#define NB_SCAN 196    // ceil(NN/256)

typedef __attribute__((ext_vector_type(4))) float f32x4;
typedef __attribute__((ext_vector_type(8))) short bf16x8;
typedef __attribute__((ext_vector_type(8))) unsigned short u16x8;

typedef const __attribute__((address_space(1))) void* gas_p;
typedef __attribute__((address_space(3))) void* las_p;

__device__ __forceinline__ float bf2f(unsigned short u) {
  union { unsigned int i; float f; } v; v.i = ((unsigned int)u) << 16; return v.f;
}
__device__ __forceinline__ unsigned short f2bf(float f) {
  union { float f; unsigned int i; } v; v.f = f;
  unsigned int u = v.i;
  return (unsigned short)((u + 0x7FFFu + ((u >> 16) & 1u)) >> 16);
}

// bijective XCD swizzle (m204)
__device__ __forceinline__ int xcd_swizzle(int orig, int nwg) {
  int xcd = orig & 7;
  int pos = orig >> 3;
  int q = nwg >> 3, r = nwg & 7;
  return (xcd < r ? xcd * (q + 1) : r * (q + 1) + (xcd - r) * q) + pos;
}

// ---------------- workspace layout (bytes, all 256-aligned) ----------------
constexpr size_t O_XBF  = 0;                  // x_bf [50000,512]bf16; reused as h0 [50000,256]bf16
constexpr size_t O_H1   = O_XBF + 51200000;   // h1 [50000,512]bf16; reused as g2
constexpr size_t O_G1   = O_H1  + 51200000;   // g1 [50000,256]bf16
constexpr size_t O_X1   = O_G1  + 25600000;   // x1 [50000,256]bf16
constexpr size_t O_H2   = O_X1  + 25600000;   // h2 [50000,64]bf16
constexpr size_t O_LG   = O_H2  + 6400000;    // Lg [50000,8]f32
constexpr size_t O_TG   = O_LG  + 1600000;    // Tg [50000,8]f32
constexpr size_t O_EWR  = O_TG  + 1600000;    // ew_raw [E]f32; reused as y3 [50000,8]f32
constexpr size_t O_W3P  = O_EWR + 3200000;    // w3p [256][8]f32 (8KB)
constexpr size_t O_CSR  = O_W3P + 3200000;    // csr_sw [E]int2 (aliased: edge1 partials, consumed first)
constexpr size_t O_MW1T = O_CSR + 6400000;    // 512*512 bf16   <- fused Bt starts here
constexpr size_t O_W1T  = O_MW1T + 524288;    // 256*512 bf16   (contiguous: 768 rows total)
constexpr size_t O_W2T  = O_W1T  + 262144;    // 256*256 bf16
constexpr size_t O_MW2T = O_W2T  + 131072;    // 64*512 bf16
constexpr size_t O_SRAW = O_MW2T + 65536;     // [N]f32 raw ew sums  <- zero block start
constexpr size_t O_CNT  = O_SRAW + 200192;    // [N]i32
constexpr size_t O_CUR  = O_CNT  + 200192;    // [N]i32
constexpr size_t O_RED  = O_CUR  + 200192;    // 2 doubles <- zero block end
constexpr size_t O_RPT  = O_RED  + 256;       // [N+1]i32
constexpr size_t O_DINV = O_RPT  + 200192;    // [N]f32
constexpr size_t O_BSUM = O_DINV + 200192;    // [NB_SCAN]i32

// ---------------- conversions ----------------
__global__ __launch_bounds__(256) void conv_f2bf4(const float* __restrict__ in,
                                                  unsigned short* __restrict__ out, int n4) {
  int i = blockIdx.x * 256 + threadIdx.x;
  if (i >= n4) return;
  const float4 v = ((const float4*)in)[i];
  ushort4 o; o.x = f2bf(v.x); o.y = f2bf(v.y); o.z = f2bf(v.z); o.w = f2bf(v.w);
  ((ushort4*)out)[i] = o;
}

__global__ __launch_bounds__(256)
void conv_weights(const float* __restrict__ mw1, const float* __restrict__ W1,
                  const float* __restrict__ W2, const float* __restrict__ mw2,
                  const float* __restrict__ W3,
                  unsigned short* __restrict__ mw1t, unsigned short* __restrict__ w1t,
                  unsigned short* __restrict__ w2t, unsigned short* __restrict__ mw2t,
                  float* __restrict__ w3p)
{
  int i = blockIdx.x * 256 + threadIdx.x;
  if (i < 262144) {                 // mw1: [512,512]
    int k = i >> 9, n = i & 511;
    mw1t[(size_t)n * 512 + k] = f2bf(mw1[i]);
  } else if (i < 393216) {          // W1: [512,256]
    int j = i - 262144, k = j >> 8, n = j & 255;
    w1t[(size_t)n * 512 + k] = f2bf(W1[j]);
  } else if (i < 458752) {          // W2: [256,256]
    int j = i - 393216, k = j >> 8, n = j & 255;
    w2t[(size_t)n * 256 + k] = f2bf(W2[j]);
  } else if (i < 491520) {          // mw2: [512,64]
    int j = i - 458752, k = j >> 6, n = j & 63;
    mw2t[(size_t)n * 512 + k] = f2bf(mw2[j]);
  } else if (i < 493568) {          // W3 pad: [256,7] -> [256,8]
    int j = i - 491520, d = j >> 3, c = j & 7;
    w3p[j] = (c < 7) ? W3[d * 7 + c] : 0.f;
  }
}

// ---------------- GEMM core: 128x128 tile, BK=64, 4 waves, 2-phase dbuf pipeline ----
#define GEMM_STAGE(buf, k0)                                                        \
  _Pragma("unroll")                                                                \
  for (int r = 0; r < 4; ++r) {                                                    \
    const int row = r * 32 + wid * 8 + srow8;                                      \
    int ga = bm + row; ga = ga < M_ ? ga : M_ - 1;                                 \
    int gb = bn + row; gb = gb < N_ ? gb : N_ - 1;                                 \
    __builtin_amdgcn_global_load_lds((gas_p)(pA_ + ((size_t)ga * lda_ + (k0)) * 2 + sks * 16), \
                                     (las_p)(ldsA[buf] + row * 64), 16, 0, 0);     \
    __builtin_amdgcn_global_load_lds((gas_p)(pB_ + ((size_t)gb * ldb_ + (k0)) * 2 + sks * 16), \
                                     (las_p)(ldsB[buf] + row * 64), 16, 0, 0);     \
  }

#define GEMM_BODY(A, lda, Bt, ldb_K, M, Ncols, K, bm, bn)                          \
  __shared__ unsigned short ldsA[2][128 * 64];                                     \
  __shared__ unsigned short ldsB[2][128 * 64];                                     \
  const char* pA_ = (const char*)(A);                                              \
  const char* pB_ = (const char*)(Bt);                                             \
  const int lda_ = (lda), ldb_ = (ldb_K), M_ = (M), N_ = (Ncols);                  \
  const int tid  = threadIdx.x;                                                    \
  const int lane = tid & 63;                                                       \
  const int wid  = tid >> 6;                                                       \
  const int wm   = (wid >> 1) << 6;                                                \
  const int wn   = (wid & 1) << 6;                                                 \
  f32x4 acc[4][4] = {};                                                            \
  const int srow8 = lane >> 3;                                                     \
  const int sks   = (lane & 7) ^ srow8;                                            \
  const int nt    = (K) >> 6;                                                      \
  GEMM_STAGE(0, 0)                                                                 \
  for (int t = 0; t < nt; ++t) {                                                   \
    const int cur = t & 1;                                                         \
    if (t + 1 < nt) {                                                              \
      GEMM_STAGE(cur ^ 1, (t + 1) << 6)                                            \
      asm volatile("s_waitcnt vmcnt(8)" ::: "memory");                             \
    } else {                                                                       \
      asm volatile("s_waitcnt vmcnt(0)" ::: "memory");                             \
    }                                                                              \
    __builtin_amdgcn_s_barrier();                                                  \
    __builtin_amdgcn_sched_barrier(0);                                             \
    const int q   = lane >> 4;                                                     \
    const int r15 = lane & 15;                                                     \
    _Pragma("unroll")                                                              \
    for (int kk = 0; kk < 2; ++kk) {                                               \
      bf16x8 af[4], bfr[4];                                                        \
      _Pragma("unroll")                                                            \
      for (int m = 0; m < 4; ++m) {                                                \
        const int ra = wm + m * 16 + r15;                                          \
        af[m]  = *(const bf16x8*)(ldsA[cur] + ra * 64 + (((kk << 2) + q) ^ (ra & 7)) * 8); \
        const int rb = wn + m * 16 + r15;                                          \
        bfr[m] = *(const bf16x8*)(ldsB[cur] + rb * 64 + (((kk << 2) + q) ^ (rb & 7)) * 8); \
      }                                                                            \
      _Pragma("unroll")                                                            \
      for (int m = 0; m < 4; ++m)                                                  \
        _Pragma("unroll")                                                          \
        for (int n = 0; n < 4; ++n)                                                \
          acc[m][n] = __builtin_amdgcn_mfma_f32_16x16x32_bf16(af[m], bfr[n], acc[m][n], 0, 0, 0); \
    }                                                                              \
    __builtin_amdgcn_sched_barrier(0);                                             \
    __builtin_amdgcn_s_barrier();                                                  \
  }

// ---------------- generic GEMM ----------------
template<bool RELU, bool BIAS>
__global__ __launch_bounds__(256)
void gemm_bf16(const unsigned short* __restrict__ A, int lda,
               const unsigned short* __restrict__ Bt,
               const float* __restrict__ bias,
               unsigned short* __restrict__ C, int ldc,
               int M, int N, int K)
{
  const int nwg  = gridDim.x * gridDim.y;
  const int wgid = xcd_swizzle(blockIdx.y * gridDim.x + blockIdx.x, nwg);
  const int bn   = (wgid % gridDim.x) << 7;
  const int bm   = (wgid / gridDim.x) << 7;

  GEMM_BODY(A, lda, Bt, K, M, N, K, bm, bn)

  const int q   = lane >> 4;
  const int r15 = lane & 15;
#pragma unroll
  for (int m = 0; m < 4; ++m) {
#pragma unroll
    for (int n = 0; n < 4; ++n) {
      const int gc = bn + wn + n * 16 + r15;
#pragma unroll
      for (int i = 0; i < 4; ++i) {
        const int gr = bm + wm + m * 16 + q * 4 + i;
        if (gr < M && gc < N) {
          float f = acc[m][n][i];
          if (BIAS) f += bias[gc];
          if (RELU) f = fmaxf(f, 0.f);
          C[(size_t)gr * ldc + gc] = f2bf(f);
        }
      }
    }
  }
}

// ---------------- fused MLP1+GCN1 GEMM: A=x_bf [M,512], Bt=[768,512] ----------------
__global__ __launch_bounds__(256)
void gemm_fused(const unsigned short* __restrict__ A,
                const unsigned short* __restrict__ Bt,
                const float* __restrict__ mb1,
                unsigned short* __restrict__ h1,
                unsigned short* __restrict__ g1,
                int M)
{
  const int nwg  = gridDim.x * gridDim.y;
  const int wgid = xcd_swizzle(blockIdx.y * gridDim.x + blockIdx.x, nwg);
  const int bnt  = wgid % gridDim.x;
  const int bn   = bnt << 7;
  const int bm   = (wgid / gridDim.x) << 7;

  GEMM_BODY(A, 512, Bt, 512, M, 768, 512, bm, bn)

  const int q   = lane >> 4;
  const int r15 = lane & 15;
  if (bnt < 4) {   // h1: bias + relu
#pragma unroll
    for (int m = 0; m < 4; ++m) {
#pragma unroll
      for (int n = 0; n < 4; ++n) {
        const int gc = bn + wn + n * 16 + r15;
        const float b = mb1[gc];
#pragma unroll
        for (int i = 0; i < 4; ++i) {
          const int gr = bm + wm + m * 16 + q * 4 + i;
          if (gr < M) h1[(size_t)gr * 512 + gc] = f2bf(fmaxf(acc[m][n][i] + b, 0.f));
        }
      }
    }
  } else {         // g1: plain
#pragma unroll
    for (int m = 0; m < 4; ++m) {
#pragma unroll
      for (int n = 0; n < 4; ++n) {
        const int gc = bn - 512 + wn + n * 16 + r15;
#pragma unroll
        for (int i = 0; i < 4; ++i) {
          const int gr = bm + wm + m * 16 + q * 4 + i;
          if (gr < M) g1[(size_t)gr * 256 + gc] = f2bf(acc[m][n][i]);
        }
      }
    }
  }
}

// ---------------- logits ----------------
__global__ __launch_bounds__(256)
void logits_kernel(const unsigned short* __restrict__ h2, const float* __restrict__ mw3,
                   const float* __restrict__ mb3, const float* __restrict__ par,
                   float* __restrict__ Lg, float* __restrict__ Tg)
{
  __shared__ float w[64 * 8];
  __shared__ float P[64];
  int tid = threadIdx.x;
  for (int i = tid; i < 512; i += 256) {
    int k = i >> 3, c = i & 7;
    w[i] = (c < 7) ? mw3[k * 7 + c] : 0.f;
  }
  if (tid < 64) {
    int d = tid >> 3, c = tid & 7;
    P[tid] = (d < 7 && c < 7) ? fmaxf(2.0f * par[d * 7 + c], 0.f) : 0.f;
  }
  __syncthreads();
  int n = blockIdx.x * 256 + tid;
  if (n >= NN) return;
  const unsigned short* hr = h2 + (size_t)n * 64;
  f32x4 L0 = {0,0,0,0}, L1 = {0,0,0,0};
  for (int k = 0; k < 64; k += 4) {
    ushort4 v = *(const ushort4*)(hr + k);
    float xs[4] = {bf2f(v.x), bf2f(v.y), bf2f(v.z), bf2f(v.w)};
#pragma unroll
    for (int j = 0; j < 4; ++j) {
      L0 += xs[j] * *(const f32x4*)&w[(k + j) * 8];
      L1 += xs[j] * *(const f32x4*)&w[(k + j) * 8 + 4];
    }
  }
  float Ls[8] = {L0[0], L0[1], L0[2], L0[3], L1[0], L1[1], L1[2], 0.f};
#pragma unroll
  for (int c = 0; c < 7; ++c) Ls[c] += mb3[c];
  f32x4 T0 = {0,0,0,0}, T1 = {0,0,0,0};
#pragma unroll
  for (int d = 0; d < 7; ++d) {
    T0 += Ls[d] * *(const f32x4*)&P[d * 8];
    T1 += Ls[d] * *(const f32x4*)&P[d * 8 + 4];
  }
  f32x4 o0 = {Ls[0], Ls[1], Ls[2], Ls[3]};
  f32x4 o1 = {Ls[4], Ls[5], Ls[6], 0.f};
  *(f32x4*)(Lg + (size_t)n * 8)     = o0;
  *(f32x4*)(Lg + (size_t)n * 8 + 4) = o1;
  *(f32x4*)(Tg + (size_t)n * 8)     = T0;
  *(f32x4*)(Tg + (size_t)n * 8 + 4) = T1;
}

// ---------------- edge pass 1: 2 edges/thread; raw ew + cnt + raw-sum per dst + partials ----
__global__ __launch_bounds__(256)
void edge1_kernel(const int* __restrict__ row, const int* __restrict__ col,
                  const float* __restrict__ Lg, const float* __restrict__ Tg,
                  float* __restrict__ ew_raw, int* __restrict__ cnt,
                  float* __restrict__ sraw, double* __restrict__ part)
{
  __shared__ double shs[4], shs2[4];
  const int e0 = blockIdx.x * 512 + threadIdx.x;
  const int e1 = e0 + 256;
  double s = 0.0, s2 = 0.0;
  if (e1 < EE) {
    int r0 = row[e0], c0 = col[e0];
    int r1 = row[e1], c1 = col[e1];
    float4 a00 = *(const float4*)(Lg + (size_t)r0 * 8);
    float4 a01 = *(const float4*)(Lg + (size_t)r0 * 8 + 4);
    float4 a10 = *(const float4*)(Lg + (size_t)r1 * 8);
    float4 a11 = *(const float4*)(Lg + (size_t)r1 * 8 + 4);
    float4 b00 = *(const float4*)(Tg + (size_t)c0 * 8);
    float4 b01 = *(const float4*)(Tg + (size_t)c0 * 8 + 4);
    float4 b10 = *(const float4*)(Tg + (size_t)c1 * 8);
    float4 b11 = *(const float4*)(Tg + (size_t)c1 * 8 + 4);
    float v0 = a00.x*b00.x + a00.y*b00.y + a00.z*b00.z + a00.w*b00.w
             + a01.x*b01.x + a01.y*b01.y + a01.z*b01.z + a01.w*b01.w;
    float v1 = a10.x*b10.x + a10.y*b10.y + a10.z*b10.z + a10.w*b10.w
             + a11.x*b11.x + a11.y*b11.y + a11.z*b11.z + a11.w*b11.w;
    ew_raw[e0] = v0; ew_raw[e1] = v1;
    atomicAdd(&cnt[c0], 1); atomicAdd(&cnt[c1], 1);
    atomicAdd(&sraw[c0], v0); atomicAdd(&sraw[c1], v1);
    s = (double)v0 + (double)v1;
    s2 = (double)v0 * (double)v0 + (double)v1 * (double)v1;
  } else if (e0 < EE) {
    int r0 = row[e0], c0 = col[e0];
    float4 a00 = *(const float4*)(Lg + (size_t)r0 * 8);
    float4 a01 = *(const float4*)(Lg + (size_t)r0 * 8 + 4);
    float4 b00 = *(const float4*)(Tg + (size_t)c0 * 8);
    float4 b01 = *(const float4*)(Tg + (size_t)c0 * 8 + 4);
    float v0 = a00.x*b00.x + a00.y*b00.y + a00.z*b00.z + a00.w*b00.w
             + a01.x*b01.x + a01.y*b01.y + a01.z*b01.z + a01.w*b01.w;
    ew_raw[e0] = v0;
    atomicAdd(&cnt[c0], 1);
    atomicAdd(&sraw[c0], v0);
    s = (double)v0; s2 = (double)v0 * (double)v0;
  }
  for (int off = 32; off; off >>= 1) {
    s  += __shfl_down(s, off);
    s2 += __shfl_down(s2, off);
  }
  int wv = threadIdx.x >> 6;
  if ((threadIdx.x & 63) == 0) { shs[wv] = s; shs2[wv] = s2; }
  __syncthreads();
  if (threadIdx.x == 0) {
    part[blockIdx.x]         = shs[0] + shs[1] + shs[2] + shs[3];
    part[NB_E1 + blockIdx.x] = shs2[0] + shs2[1] + shs2[2] + shs2[3];
  }
}

// ---------------- reduce edge1 partials -> red ----------------
__global__ __launch_bounds__(1024)
void redpart_kernel(const double* __restrict__ part, double* __restrict__ red)
{
  __shared__ double sh[16][2];
  int tid = threadIdx.x;
  double s = 0.0, s2 = 0.0;
  for (int i = tid; i < NB_E1; i += 1024) {
    s  += part[i];
    s2 += part[NB_E1 + i];
  }
  for (int off = 32; off; off >>= 1) {
    s  += __shfl_down(s, off);
    s2 += __shfl_down(s2, off);
  }
  if ((tid & 63) == 0) { sh[tid >> 6][0] = s; sh[tid >> 6][1] = s2; }
  __syncthreads();
  if (tid == 0) {
    double a = 0.0, b = 0.0;
    for (int i = 0; i < 16; ++i) { a += sh[i][0]; b += sh[i][1]; }
    red[0] = a; red[1] = b;
  }
}

// ---------------- dinv from raw sums: deg_c = scl*(Sraw_c - cnt_c*mean) + cnt_c ----------------
__global__ __launch_bounds__(256)
void dinv_kernel(const float* __restrict__ sraw, const int* __restrict__ cnt,
                 const double* __restrict__ red, float* __restrict__ dinv)
{
  int n = blockIdx.x * 256 + threadIdx.x;
  if (n >= NN) return;
  double mean = red[0] / (double)EE;
  double var  = (red[1] - (double)EE * mean * mean) / (double)(EE - 1);
  double scl  = sqrt(1e-4 / var);
  double c    = (double)cnt[n];
  double deg  = scl * ((double)sraw[n] - c * mean) + c;
  float d = (float)deg + 1.0f;   // + self-loop weight 1
  dinv[n] = d > 0.f ? 1.0f / sqrtf(fmaxf(d, 1e-12f)) : 0.f;
}

// ---------------- edge pass 2: standardize + CSR fill (src, ew_std*dinv[src]) ----------------
__global__ __launch_bounds__(256)
void edge2_kernel(const int* __restrict__ row, const int* __restrict__ col,
                  const float* __restrict__ ew_raw, const double* __restrict__ red,
                  const int* __restrict__ rowptr, int* __restrict__ cursor,
                  const float* __restrict__ dinv, int2* __restrict__ csr_sw)
{
  int e = blockIdx.x * 256 + threadIdx.x;
  if (e >= EE) return;
  double mean = red[0] / (double)EE;
  double var  = (red[1] - (double)EE * mean * mean) / (double)(EE - 1);
  double scl  = sqrt(1e-4 / var);
  float v = (float)(((double)ew_raw[e] - mean) * scl) + 1.0f;
  int r = row[e], c = col[e];
  float w = v * dinv[r];
  int pos = atomicAdd(&cursor[c], 1);
  int2 sw; sw.x = r; sw.y = __float_as_int(w);
  csr_sw[rowptr[c] + pos] = sw;
}

// ---------------- parallel 3-stage exclusive scan of cnt -> rowptr ----------------
__global__ __launch_bounds__(256)
void scan1_kernel(const int* __restrict__ cnt, int* __restrict__ bsum)
{
  __shared__ int sh[4];
  int i = blockIdx.x * 256 + threadIdx.x;
  int v = (i < NN) ? cnt[i] : 0;
  for (int off = 32; off; off >>= 1) v += __shfl_down(v, off);
  if ((threadIdx.x & 63) == 0) sh[threadIdx.x >> 6] = v;
  __syncthreads();
  if (threadIdx.x == 0) bsum[blockIdx.x] = sh[0] + sh[1] + sh[2] + sh[3];
}

__global__ __launch_bounds__(256)
void scan2_kernel(int* __restrict__ bsum)
{
  __shared__ int sh[256];
  int tid = threadIdx.x;
  int v = (tid < NB_SCAN) ? bsum[tid] : 0;
  sh[tid] = v;
  __syncthreads();
  for (int off = 1; off < 256; off <<= 1) {
    int t = (tid >= off) ? sh[tid - off] : 0;
    __syncthreads();
    sh[tid] += t;
    __syncthreads();
  }
  if (tid < NB_SCAN) bsum[tid] = sh[tid] - v;   // exclusive
}

__global__ __launch_bounds__(256)
void scan3_kernel(const int* __restrict__ cnt, const int* __restrict__ bsum,
                  int* __restrict__ rowptr)
{
  __shared__ int sh[256];
  int tid = threadIdx.x;
  int i = blockIdx.x * 256 + tid;
  int v = (i < NN) ? cnt[i] : 0;
  sh[tid] = v;
  __syncthreads();
  for (int off = 1; off < 256; off <<= 1) {
    int t = (tid >= off) ? sh[tid - off] : 0;
    __syncthreads();
    sh[tid] += t;
    __syncthreads();
  }
  if (i < NN) rowptr[i + 1] = bsum[blockIdx.x] + sh[tid];
  if (i == 0) rowptr[0] = 0;
}

// ---------------- dim-256 aggregation: one node per HALF-WAVE, persistent grid ----
// grid must equal resident capacity: 6 blocks/CU * 256 CU = 1536 (launch_bounds(256,6))
#define AGG_ACC(sw_, v_)                                                     \
  {                                                                          \
    float w_ = __int_as_float((sw_).y);                                      \
    a0 += w_ * bf2f((v_)[0]); a1 += w_ * bf2f((v_)[1]);                      \
    a2 += w_ * bf2f((v_)[2]); a3 += w_ * bf2f((v_)[3]);                      \
    a4 += w_ * bf2f((v_)[4]); a5 += w_ * bf2f((v_)[5]);                      \
    a6 += w_ * bf2f((v_)[6]); a7 += w_ * bf2f((v_)[7]);                      \
  }

template<int MODE>
__global__ __launch_bounds__(256, 6)
void agg256_kernel(const int* __restrict__ rowptr, const int2* __restrict__ csr_sw,
                   const unsigned short* __restrict__ gsrc,
                   const float* __restrict__ dinv, const float* __restrict__ bias,
                   const unsigned short* __restrict__ h0in,
                   unsigned short* __restrict__ h0out,
                   unsigned short* __restrict__ xout,
                   const float* __restrict__ w3p, float* __restrict__ y3)
{
  const int tid = threadIdx.x;
  const int hw  = tid >> 5;          // half-wave 0..7
  const int l5  = tid & 31;
  const size_t colbase = (size_t)(l5 << 3);
  const int stride = (int)gridDim.x * 8;

  for (int n = blockIdx.x * 8 + hw; n < NN; n += stride) {
    float a0=0,a1=0,a2=0,a3=0,a4=0,a5=0,a6=0,a7=0;
    const int s = rowptr[n], e = rowptr[n + 1];
    int i = s;
    for (; i + 7 < e; i += 8) {               // 8 gathers in flight
      int2 sw[8];
#pragma unroll
      for (int u = 0; u < 8; ++u) sw[u] = csr_sw[i + u];
      u16x8 v[8];
#pragma unroll
      for (int u = 0; u < 8; ++u) v[u] = *(const u16x8*)(gsrc + (size_t)sw[u].x * 256 + colbase);
#pragma unroll
      for (int u = 0; u < 8; ++u) AGG_ACC(sw[u], v[u])
    }
    for (; i + 3 < e; i += 4) {
      int2 sw[4];
#pragma unroll
      for (int u = 0; u < 4; ++u) sw[u] = csr_sw[i + u];
      u16x8 v[4];
#pragma unroll
      for (int u = 0; u < 4; ++u) v[u] = *(const u16x8*)(gsrc + (size_t)sw[u].x * 256 + colbase);
#pragma unroll
      for (int u = 0; u < 4; ++u) AGG_ACC(sw[u], v[u])
    }
    for (; i < e; ++i) {
      int2 sw = csr_sw[i];
      u16x8 v = *(const u16x8*)(gsrc + (size_t)sw.x * 256 + colbase);
      AGG_ACC(sw, v)
    }
    const int dbase = l5 << 3;
    const float dn = dinv[n];
    const float wd = dn * dn;
    u16x8 sv = *(const u16x8*)(gsrc + (size_t)n * 256 + dbase);
    float4 b0 = *(const float4*)(bias + dbase);
    float4 b1 = *(const float4*)(bias + dbase + 4);
    float f0 = dn * a0 + wd * bf2f(sv[0]) + b0.x;
    float f1 = dn * a1 + wd * bf2f(sv[1]) + b0.y;
    float f2 = dn * a2 + wd * bf2f(sv[2]) + b0.z;
    float f3 = dn * a3 + wd * bf2f(sv[3]) + b0.w;
    float f4 = dn * a4 + wd * bf2f(sv[4]) + b1.x;
    float f5 = dn * a5 + wd * bf2f(sv[5]) + b1.y;
    float f6 = dn * a6 + wd * bf2f(sv[6]) + b1.z;
    float f7 = dn * a7 + wd * bf2f(sv[7]) + b1.w;
    const size_t o = (size_t)n * 256 + dbase;
    if (MODE == 0) {
      u16x8 h;
      h[0] = f2bf(f0); h[1] = f2bf(f1); h[2] = f2bf(f2); h[3] = f2bf(f3);
      h[4] = f2bf(f4); h[5] = f2bf(f5); h[6] = f2bf(f6); h[7] = f2bf(f7);
      *(u16x8*)(h0out + o) = h;
      u16x8 xo;
      xo[0] = f2bf(fmaxf(f0, 0.f)); xo[1] = f2bf(fmaxf(f1, 0.f));
      xo[2] = f2bf(fmaxf(f2, 0.f)); xo[3] = f2bf(fmaxf(f3, 0.f));
      xo[4] = f2bf(fmaxf(f4, 0.f)); xo[5] = f2bf(fmaxf(f5, 0.f));
      xo[6] = f2bf(fmaxf(f6, 0.f)); xo[7] = f2bf(fmaxf(f7, 0.f));
      *(u16x8*)(xout + o) = xo;
    } else {
      u16x8 h = *(const u16x8*)(h0in + o);
      float xv0 = bf2f(f2bf(fmaxf(f0, 0.f) + bf2f(h[0])));
      float xv1 = bf2f(f2bf(fmaxf(f1, 0.f) + bf2f(h[1])));
      float xv2 = bf2f(f2bf(fmaxf(f2, 0.f) + bf2f(h[2])));
      float xv3 = bf2f(f2bf(fmaxf(f3, 0.f) + bf2f(h[3])));
      float xv4 = bf2f(f2bf(fmaxf(f4, 0.f) + bf2f(h[4])));
      float xv5 = bf2f(f2bf(fmaxf(f5, 0.f) + bf2f(h[5])));
      float xv6 = bf2f(f2bf(fmaxf(f6, 0.f) + bf2f(h[6])));
      float xv7 = bf2f(f2bf(fmaxf(f7, 0.f) + bf2f(h[7])));
      const float* w3r = w3p + (size_t)dbase * 8;
      f32x4 p0 = {0,0,0,0}, p1 = {0,0,0,0};
      p0 += xv0 * *(const f32x4*)(w3r +  0); p1 += xv0 * *(const f32x4*)(w3r +  4);
      p0 += xv1 * *(const f32x4*)(w3r +  8); p1 += xv1 * *(const f32x4*)(w3r + 12);
      p0 += xv2 * *(const f32x4*)(w3r + 16); p1 += xv2 * *(const f32x4*)(w3r + 20);
      p0 += xv3 * *(const f32x4*)(w3r + 24); p1 += xv3 * *(const f32x4*)(w3r + 28);
      p0 += xv4 * *(const f32x4*)(w3r + 32); p1 += xv4 * *(const f32x4*)(w3r + 36);
      p0 += xv5 * *(const f32x4*)(w3r + 40); p1 += xv5 * *(const f32x4*)(w3r + 44);
      p0 += xv6 * *(const f32x4*)(w3r + 48); p1 += xv6 * *(const f32x4*)(w3r + 52);
      p0 += xv7 * *(const f32x4*)(w3r + 56); p1 += xv7 * *(const f32x4*)(w3r + 60);
#pragma unroll
      for (int off = 1; off < 32; off <<= 1) {
        p0[0] += __shfl_xor(p0[0], off); p0[1] += __shfl_xor(p0[1], off);
        p0[2] += __shfl_xor(p0[2], off); p0[3] += __shfl_xor(p0[3], off);
        p1[0] += __shfl_xor(p1[0], off); p1[1] += __shfl_xor(p1[1], off);
        p1[2] += __shfl_xor(p1[2], off); p1[3] += __shfl_xor(p1[3], off);
      }
      if (l5 == 0) {
        *(f32x4*)(y3 + (size_t)n * 8)     = p0;
        *(f32x4*)(y3 + (size_t)n * 8 + 4) = p1;
      }
    }
  }
}

// ---------------- dim-7 aggregation: 8 lanes per node, 4-deep ILP ----------------
__global__ __launch_bounds__(256)
void agg7_kernel(const int* __restrict__ rowptr, const int2* __restrict__ csr_sw,
                 const float* __restrict__ y3,
                 const float* __restrict__ dinv, const float* __restrict__ b3,
                 float* __restrict__ out)
{
  int n = blockIdx.x * 32 + (threadIdx.x >> 3);
  if (n >= NN) return;
  int j = threadIdx.x & 7;
  float acc = 0.f;
  int s = rowptr[n], e = rowptr[n + 1];
  int i = s;
  for (; i + 3 < e; i += 4) {
    int2 sw0 = csr_sw[i],     sw1 = csr_sw[i + 1];
    int2 sw2 = csr_sw[i + 2], sw3 = csr_sw[i + 3];
    float v0 = y3[(size_t)sw0.x * 8 + j];
    float v1 = y3[(size_t)sw1.x * 8 + j];
    float v2 = y3[(size_t)sw2.x * 8 + j];
    float v3 = y3[(size_t)sw3.x * 8 + j];
    acc += __int_as_float(sw0.y) * v0 + __int_as_float(sw1.y) * v1
         + __int_as_float(sw2.y) * v2 + __int_as_float(sw3.y) * v3;
  }
  for (; i < e; ++i) {
    int2 sw = csr_sw[i];
    acc += __int_as_float(sw.y) * y3[(size_t)sw.x * 8 + j];
  }
  float dn = dinv[n];
  acc = dn * acc + dn * dn * y3[(size_t)n * 8 + j];
  if (j < 7) out[(size_t)n * 7 + j] = acc + b3[j];
}

// ---------------- host ----------------
extern "C" void kernel_launch(void* const* d_in, const int* in_sizes, int n_in,
                              void* d_out, int out_size, void* d_ws, size_t ws_size,
                              hipStream_t stream)
{
  const float* x   = (const float*)d_in[0];
  const int*   ei  = (const int*)d_in[1];
  const float* W1  = (const float*)d_in[2];
  const float* b1  = (const float*)d_in[3];
  const float* W2  = (const float*)d_in[4];
  const float* b2  = (const float*)d_in[5];
  const float* W3  = (const float*)d_in[6];
  const float* b3  = (const float*)d_in[7];
  const float* mw1 = (const float*)d_in[8];
  const float* mb1 = (const float*)d_in[9];
  const float* mw2 = (const float*)d_in[10];
  const float* mb2 = (const float*)d_in[11];
  const float* mw3 = (const float*)d_in[12];
  const float* mb3 = (const float*)d_in[13];
  const float* par = (const float*)d_in[14];
  const int* row = ei;
  const int* col = ei + EE;
  float* out = (float*)d_out;

  char* ws = (char*)d_ws;
  unsigned short* x_bf  = (unsigned short*)(ws + O_XBF);
  unsigned short* h0    = (unsigned short*)(ws + O_XBF);   // bf16, alias (x_bf dead after fused GEMM)
  unsigned short* h1_bf = (unsigned short*)(ws + O_H1);
  unsigned short* g2_bf = (unsigned short*)(ws + O_H1);    // reuse (h1 dead)
  unsigned short* g1_bf = (unsigned short*)(ws + O_G1);
  unsigned short* x1_bf = (unsigned short*)(ws + O_X1);
  unsigned short* h2_bf = (unsigned short*)(ws + O_H2);
  float* Lg      = (float*)(ws + O_LG);
  float* Tg      = (float*)(ws + O_TG);
  float* ew_raw  = (float*)(ws + O_EWR);
  float* y3      = (float*)(ws + O_EWR);                   // reuse (ew_raw dead after edge2)
  float* w3p     = (float*)(ws + O_W3P);
  int2*  csr_sw  = (int2*)(ws + O_CSR);
  double* part   = (double*)(ws + O_CSR);                  // alias: consumed before edge2 fills csr
  unsigned short* mw1t = (unsigned short*)(ws + O_MW1T);   // fused Bt = [mw1t; w1t], 768 rows
  unsigned short* w1t  = (unsigned short*)(ws + O_W1T);
  unsigned short* w2t  = (unsigned short*)(ws + O_W2T);
  unsigned short* mw2t = (unsigned short*)(ws + O_MW2T);
  float*  sraw   = (float*)(ws + O_SRAW);
  int*    cnt    = (int*)(ws + O_CNT);
  int*    cursor = (int*)(ws + O_CUR);
  double* red    = (double*)(ws + O_RED);
  int*    rowptr = (int*)(ws + O_RPT);
  float*  dinv   = (float*)(ws + O_DINV);
  int*    bsum   = (int*)(ws + O_BSUM);

  // zero: sraw, cnt, cursor (contiguous)
  hipMemsetAsync(ws + O_SRAW, 0, 3 * 200192, stream);

  // fp32 -> bf16 conversions (+ padded W3)
  conv_f2bf4<<<25000, 256, 0, stream>>>(x, x_bf, NN * 512 / 4);
  conv_weights<<<1929, 256, 0, stream>>>(mw1, W1, W2, mw2, W3, mw1t, w1t, w2t, mw2t, w3p);

  // fused MLP1 + GCN1 GEMM
  gemm_fused<<<dim3(6, 391), 256, 0, stream>>>(x_bf, mw1t, mb1, h1_bf, g1_bf, NN);
  // MLP layer 2
  gemm_bf16<true,  true ><<<dim3(1, 391), 256, 0, stream>>>(h1_bf, 512, mw2t, mb2, h2_bf, 64, NN, 64, 512);
  logits_kernel<<<196, 256, 0, stream>>>(h2_bf, mw3, mb3, par, Lg, Tg);

  // edge weights + CSR (deg derived from raw sums; dinv before edge2; CSR stores final weight)
  edge1_kernel<<<NB_E1, 256, 0, stream>>>(row, col, Lg, Tg, ew_raw, cnt, sraw, part);
  redpart_kernel<<<1, 1024, 0, stream>>>(part, red);
  scan1_kernel<<<NB_SCAN, 256, 0, stream>>>(cnt, bsum);
  scan2_kernel<<<1, 256, 0, stream>>>(bsum);
  scan3_kernel<<<NB_SCAN, 256, 0, stream>>>(cnt, bsum, rowptr);
  dinv_kernel<<<196, 256, 0, stream>>>(sraw, cnt, red, dinv);
  edge2_kernel<<<NB_EDGE, 256, 0, stream>>>(row, col, ew_raw, red, rowptr, cursor, dinv, csr_sw);

  // GCN layer 0 aggregation (g1 from fused GEMM) -- persistent, grid == resident capacity
  agg256_kernel<0><<<1536, 256, 0, stream>>>(rowptr, csr_sw, g1_bf, dinv, b1, nullptr, h0, x1_bf, nullptr, nullptr);
  // GCN layer 1 (+residual h0), fused with W3 gemv -> y3
  gemm_bf16<false, false><<<dim3(2, 391), 256, 0, stream>>>(x1_bf, 256, w2t, nullptr, g2_bf, 256, NN, 256, 256);
  agg256_kernel<1><<<1536, 256, 0, stream>>>(rowptr, csr_sw, g2_bf, dinv, b2, h0, nullptr, nullptr, w3p, y3);
  // final dim-7 aggregation
  agg7_kernel<<<1563, 256, 0, stream>>>(rowptr, csr_sw, y3, dinv, b3, out);
}

// Round 12
// 431.937 us; speedup vs baseline: 1.1725x; 1.1725x over previous
//
#include <hip/hip_runtime.h>

#define NN 50000
#define EE 800000
#define NB_EDGE 3125   // ceil(EE/256)
#define NB_E1   1563   // ceil(EE/512)
#define NB_SCAN 196    // ceil(NN/256)

typedef __attribute__((ext_vector_type(4))) float f32x4;
typedef __attribute__((ext_vector_type(8))) short bf16x8;
typedef __attribute__((ext_vector_type(8))) unsigned short u16x8;

typedef const __attribute__((address_space(1))) void* gas_p;
typedef __attribute__((address_space(3))) void* las_p;

__device__ __forceinline__ float bf2f(unsigned short u) {
  union { unsigned int i; float f; } v; v.i = ((unsigned int)u) << 16; return v.f;
}
__device__ __forceinline__ unsigned short f2bf(float f) {
  union { float f; unsigned int i; } v; v.f = f;
  unsigned int u = v.i;
  return (unsigned short)((u + 0x7FFFu + ((u >> 16) & 1u)) >> 16);
}

// bijective XCD swizzle (m204)
__device__ __forceinline__ int xcd_swizzle(int orig, int nwg) {
  int xcd = orig & 7;
  int pos = orig >> 3;
  int q = nwg >> 3, r = nwg & 7;
  return (xcd < r ? xcd * (q + 1) : r * (q + 1) + (xcd - r) * q) + pos;
}

// ---------------- workspace layout (bytes, all 256-aligned) ----------------
constexpr size_t O_XBF  = 0;                  // x_bf [50000,512]bf16; reused as h0 [50000,256]bf16
constexpr size_t O_H1   = O_XBF + 51200000;   // h1 [50000,512]bf16; reused as g2
constexpr size_t O_G1   = O_H1  + 51200000;   // g1 [50000,256]bf16
constexpr size_t O_X1   = O_G1  + 25600000;   // x1 [50000,256]bf16
constexpr size_t O_H2   = O_X1  + 25600000;   // h2 [50000,64]bf16
constexpr size_t O_LG   = O_H2  + 6400000;    // Lg [50000,8]f32
constexpr size_t O_TG   = O_LG  + 1600000;    // Tg [50000,8]f32
constexpr size_t O_EWR  = O_TG  + 1600000;    // ew_raw [E]f32; reused as y3 [50000,8]f32
constexpr size_t O_W3P  = O_EWR + 3200000;    // w3p [256][8]f32 (8KB)
constexpr size_t O_CSR  = O_W3P + 3200000;    // csr_sw [E]int2 (aliased: edge1 partials, consumed first)
constexpr size_t O_MW1T = O_CSR + 6400000;    // 512*512 bf16   <- fused Bt starts here
constexpr size_t O_W1T  = O_MW1T + 524288;    // 256*512 bf16   (contiguous: 768 rows total)
constexpr size_t O_W2T  = O_W1T  + 262144;    // 256*256 bf16
constexpr size_t O_MW2T = O_W2T  + 131072;    // 64*512 bf16
constexpr size_t O_SRAW = O_MW2T + 65536;     // [N]f32 raw ew sums  <- zero block start
constexpr size_t O_CNT  = O_SRAW + 200192;    // [N]i32
constexpr size_t O_CUR  = O_CNT  + 200192;    // [N]i32
constexpr size_t O_RED  = O_CUR  + 200192;    // 2 doubles <- zero block end
constexpr size_t O_RPT  = O_RED  + 256;       // [N+1]i32
constexpr size_t O_DINV = O_RPT  + 200192;    // [N]f32
constexpr size_t O_BSUM = O_DINV + 200192;    // [NB_SCAN]i32

// ---------------- conversions ----------------
__global__ __launch_bounds__(256) void conv_f2bf4(const float* __restrict__ in,
                                                  unsigned short* __restrict__ out, int n4) {
  int i = blockIdx.x * 256 + threadIdx.x;
  if (i >= n4) return;
  const float4 v = ((const float4*)in)[i];
  ushort4 o; o.x = f2bf(v.x); o.y = f2bf(v.y); o.z = f2bf(v.z); o.w = f2bf(v.w);
  ((ushort4*)out)[i] = o;
}

__global__ __launch_bounds__(256)
void conv_weights(const float* __restrict__ mw1, const float* __restrict__ W1,
                  const float* __restrict__ W2, const float* __restrict__ mw2,
                  const float* __restrict__ W3,
                  unsigned short* __restrict__ mw1t, unsigned short* __restrict__ w1t,
                  unsigned short* __restrict__ w2t, unsigned short* __restrict__ mw2t,
                  float* __restrict__ w3p)
{
  int i = blockIdx.x * 256 + threadIdx.x;
  if (i < 262144) {                 // mw1: [512,512]
    int k = i >> 9, n = i & 511;
    mw1t[(size_t)n * 512 + k] = f2bf(mw1[i]);
  } else if (i < 393216) {          // W1: [512,256]
    int j = i - 262144, k = j >> 8, n = j & 255;
    w1t[(size_t)n * 512 + k] = f2bf(W1[j]);
  } else if (i < 458752) {          // W2: [256,256]
    int j = i - 393216, k = j >> 8, n = j & 255;
    w2t[(size_t)n * 256 + k] = f2bf(W2[j]);
  } else if (i < 491520) {          // mw2: [512,64]
    int j = i - 458752, k = j >> 6, n = j & 63;
    mw2t[(size_t)n * 512 + k] = f2bf(mw2[j]);
  } else if (i < 493568) {          // W3 pad: [256,7] -> [256,8]
    int j = i - 491520, d = j >> 3, c = j & 7;
    w3p[j] = (c < 7) ? W3[d * 7 + c] : 0.f;
  }
}

// ---------------- GEMM core: 128x128 tile, BK=64, 4 waves, 2-phase dbuf pipeline ----
#define GEMM_STAGE(buf, k0)                                                        \
  _Pragma("unroll")                                                                \
  for (int r = 0; r < 4; ++r) {                                                    \
    const int row = r * 32 + wid * 8 + srow8;                                      \
    int ga = bm + row; ga = ga < M_ ? ga : M_ - 1;                                 \
    int gb = bn + row; gb = gb < N_ ? gb : N_ - 1;                                 \
    __builtin_amdgcn_global_load_lds((gas_p)(pA_ + ((size_t)ga * lda_ + (k0)) * 2 + sks * 16), \
                                     (las_p)(ldsA[buf] + row * 64), 16, 0, 0);     \
    __builtin_amdgcn_global_load_lds((gas_p)(pB_ + ((size_t)gb * ldb_ + (k0)) * 2 + sks * 16), \
                                     (las_p)(ldsB[buf] + row * 64), 16, 0, 0);     \
  }

#define GEMM_BODY(A, lda, Bt, ldb_K, M, Ncols, K, bm, bn)                          \
  __shared__ unsigned short ldsA[2][128 * 64];                                     \
  __shared__ unsigned short ldsB[2][128 * 64];                                     \
  const char* pA_ = (const char*)(A);                                              \
  const char* pB_ = (const char*)(Bt);                                             \
  const int lda_ = (lda), ldb_ = (ldb_K), M_ = (M), N_ = (Ncols);                  \
  const int tid  = threadIdx.x;                                                    \
  const int lane = tid & 63;                                                       \
  const int wid  = tid >> 6;                                                       \
  const int wm   = (wid >> 1) << 6;                                                \
  const int wn   = (wid & 1) << 6;                                                 \
  f32x4 acc[4][4] = {};                                                            \
  const int srow8 = lane >> 3;                                                     \
  const int sks   = (lane & 7) ^ srow8;                                            \
  const int nt    = (K) >> 6;                                                      \
  GEMM_STAGE(0, 0)                                                                 \
  for (int t = 0; t < nt; ++t) {                                                   \
    const int cur = t & 1;                                                         \
    if (t + 1 < nt) {                                                              \
      GEMM_STAGE(cur ^ 1, (t + 1) << 6)                                            \
      asm volatile("s_waitcnt vmcnt(8)" ::: "memory");                             \
    } else {                                                                       \
      asm volatile("s_waitcnt vmcnt(0)" ::: "memory");                             \
    }                                                                              \
    __builtin_amdgcn_s_barrier();                                                  \
    __builtin_amdgcn_sched_barrier(0);                                             \
    const int q   = lane >> 4;                                                     \
    const int r15 = lane & 15;                                                     \
    _Pragma("unroll")                                                              \
    for (int kk = 0; kk < 2; ++kk) {                                               \
      bf16x8 af[4], bfr[4];                                                        \
      _Pragma("unroll")                                                            \
      for (int m = 0; m < 4; ++m) {                                                \
        const int ra = wm + m * 16 + r15;                                          \
        af[m]  = *(const bf16x8*)(ldsA[cur] + ra * 64 + (((kk << 2) + q) ^ (ra & 7)) * 8); \
        const int rb = wn + m * 16 + r15;                                          \
        bfr[m] = *(const bf16x8*)(ldsB[cur] + rb * 64 + (((kk << 2) + q) ^ (rb & 7)) * 8); \
      }                                                                            \
      _Pragma("unroll")                                                            \
      for (int m = 0; m < 4; ++m)                                                  \
        _Pragma("unroll")                                                          \
        for (int n = 0; n < 4; ++n)                                                \
          acc[m][n] = __builtin_amdgcn_mfma_f32_16x16x32_bf16(af[m], bfr[n], acc[m][n], 0, 0, 0); \
    }                                                                              \
    __builtin_amdgcn_sched_barrier(0);                                             \
    __builtin_amdgcn_s_barrier();                                                  \
  }

// ---------------- generic GEMM ----------------
template<bool RELU, bool BIAS>
__global__ __launch_bounds__(256)
void gemm_bf16(const unsigned short* __restrict__ A, int lda,
               const unsigned short* __restrict__ Bt,
               const float* __restrict__ bias,
               unsigned short* __restrict__ C, int ldc,
               int M, int N, int K)
{
  const int nwg  = gridDim.x * gridDim.y;
  const int wgid = xcd_swizzle(blockIdx.y * gridDim.x + blockIdx.x, nwg);
  const int bn   = (wgid % gridDim.x) << 7;
  const int bm   = (wgid / gridDim.x) << 7;

  GEMM_BODY(A, lda, Bt, K, M, N, K, bm, bn)

  const int q   = lane >> 4;
  const int r15 = lane & 15;
#pragma unroll
  for (int m = 0; m < 4; ++m) {
#pragma unroll
    for (int n = 0; n < 4; ++n) {
      const int gc = bn + wn + n * 16 + r15;
#pragma unroll
      for (int i = 0; i < 4; ++i) {
        const int gr = bm + wm + m * 16 + q * 4 + i;
        if (gr < M && gc < N) {
          float f = acc[m][n][i];
          if (BIAS) f += bias[gc];
          if (RELU) f = fmaxf(f, 0.f);
          C[(size_t)gr * ldc + gc] = f2bf(f);
        }
      }
    }
  }
}

// ---------------- fused MLP1+GCN1 GEMM: A=x_bf [M,512], Bt=[768,512] ----------------
__global__ __launch_bounds__(256)
void gemm_fused(const unsigned short* __restrict__ A,
                const unsigned short* __restrict__ Bt,
                const float* __restrict__ mb1,
                unsigned short* __restrict__ h1,
                unsigned short* __restrict__ g1,
                int M)
{
  const int nwg  = gridDim.x * gridDim.y;
  const int wgid = xcd_swizzle(blockIdx.y * gridDim.x + blockIdx.x, nwg);
  const int bnt  = wgid % gridDim.x;
  const int bn   = bnt << 7;
  const int bm   = (wgid / gridDim.x) << 7;

  GEMM_BODY(A, 512, Bt, 512, M, 768, 512, bm, bn)

  const int q   = lane >> 4;
  const int r15 = lane & 15;
  if (bnt < 4) {   // h1: bias + relu
#pragma unroll
    for (int m = 0; m < 4; ++m) {
#pragma unroll
      for (int n = 0; n < 4; ++n) {
        const int gc = bn + wn + n * 16 + r15;
        const float b = mb1[gc];
#pragma unroll
        for (int i = 0; i < 4; ++i) {
          const int gr = bm + wm + m * 16 + q * 4 + i;
          if (gr < M) h1[(size_t)gr * 512 + gc] = f2bf(fmaxf(acc[m][n][i] + b, 0.f));
        }
      }
    }
  } else {         // g1: plain
#pragma unroll
    for (int m = 0; m < 4; ++m) {
#pragma unroll
      for (int n = 0; n < 4; ++n) {
        const int gc = bn - 512 + wn + n * 16 + r15;
#pragma unroll
        for (int i = 0; i < 4; ++i) {
          const int gr = bm + wm + m * 16 + q * 4 + i;
          if (gr < M) g1[(size_t)gr * 256 + gc] = f2bf(acc[m][n][i]);
        }
      }
    }
  }
}

// ---------------- logits ----------------
__global__ __launch_bounds__(256)
void logits_kernel(const unsigned short* __restrict__ h2, const float* __restrict__ mw3,
                   const float* __restrict__ mb3, const float* __restrict__ par,
                   float* __restrict__ Lg, float* __restrict__ Tg)
{
  __shared__ float w[64 * 8];
  __shared__ float P[64];
  int tid = threadIdx.x;
  for (int i = tid; i < 512; i += 256) {
    int k = i >> 3, c = i & 7;
    w[i] = (c < 7) ? mw3[k * 7 + c] : 0.f;
  }
  if (tid < 64) {
    int d = tid >> 3, c = tid & 7;
    P[tid] = (d < 7 && c < 7) ? fmaxf(2.0f * par[d * 7 + c], 0.f) : 0.f;
  }
  __syncthreads();
  int n = blockIdx.x * 256 + tid;
  if (n >= NN) return;
  const unsigned short* hr = h2 + (size_t)n * 64;
  f32x4 L0 = {0,0,0,0}, L1 = {0,0,0,0};
  for (int k = 0; k < 64; k += 4) {
    ushort4 v = *(const ushort4*)(hr + k);
    float xs[4] = {bf2f(v.x), bf2f(v.y), bf2f(v.z), bf2f(v.w)};
#pragma unroll
    for (int j = 0; j < 4; ++j) {
      L0 += xs[j] * *(const f32x4*)&w[(k + j) * 8];
      L1 += xs[j] * *(const f32x4*)&w[(k + j) * 8 + 4];
    }
  }
  float Ls[8] = {L0[0], L0[1], L0[2], L0[3], L1[0], L1[1], L1[2], 0.f};
#pragma unroll
  for (int c = 0; c < 7; ++c) Ls[c] += mb3[c];
  f32x4 T0 = {0,0,0,0}, T1 = {0,0,0,0};
#pragma unroll
  for (int d = 0; d < 7; ++d) {
    T0 += Ls[d] * *(const f32x4*)&P[d * 8];
    T1 += Ls[d] * *(const f32x4*)&P[d * 8 + 4];
  }
  f32x4 o0 = {Ls[0], Ls[1], Ls[2], Ls[3]};
  f32x4 o1 = {Ls[4], Ls[5], Ls[6], 0.f};
  *(f32x4*)(Lg + (size_t)n * 8)     = o0;
  *(f32x4*)(Lg + (size_t)n * 8 + 4) = o1;
  *(f32x4*)(Tg + (size_t)n * 8)     = T0;
  *(f32x4*)(Tg + (size_t)n * 8 + 4) = T1;
}

// ---------------- edge pass 1: 2 edges/thread; raw ew + cnt + raw-sum per dst + partials ----
__global__ __launch_bounds__(256)
void edge1_kernel(const int* __restrict__ row, const int* __restrict__ col,
                  const float* __restrict__ Lg, const float* __restrict__ Tg,
                  float* __restrict__ ew_raw, int* __restrict__ cnt,
                  float* __restrict__ sraw, double* __restrict__ part)
{
  __shared__ double shs[4], shs2[4];
  const int e0 = blockIdx.x * 512 + threadIdx.x;
  const int e1 = e0 + 256;
  double s = 0.0, s2 = 0.0;
  if (e1 < EE) {
    int r0 = row[e0], c0 = col[e0];
    int r1 = row[e1], c1 = col[e1];
    float4 a00 = *(const float4*)(Lg + (size_t)r0 * 8);
    float4 a01 = *(const float4*)(Lg + (size_t)r0 * 8 + 4);
    float4 a10 = *(const float4*)(Lg + (size_t)r1 * 8);
    float4 a11 = *(const float4*)(Lg + (size_t)r1 * 8 + 4);
    float4 b00 = *(const float4*)(Tg + (size_t)c0 * 8);
    float4 b01 = *(const float4*)(Tg + (size_t)c0 * 8 + 4);
    float4 b10 = *(const float4*)(Tg + (size_t)c1 * 8);
    float4 b11 = *(const float4*)(Tg + (size_t)c1 * 8 + 4);
    float v0 = a00.x*b00.x + a00.y*b00.y + a00.z*b00.z + a00.w*b00.w
             + a01.x*b01.x + a01.y*b01.y + a01.z*b01.z + a01.w*b01.w;
    float v1 = a10.x*b10.x + a10.y*b10.y + a10.z*b10.z + a10.w*b10.w
             + a11.x*b11.x + a11.y*b11.y + a11.z*b11.z + a11.w*b11.w;
    ew_raw[e0] = v0; ew_raw[e1] = v1;
    atomicAdd(&cnt[c0], 1); atomicAdd(&cnt[c1], 1);
    atomicAdd(&sraw[c0], v0); atomicAdd(&sraw[c1], v1);
    s = (double)v0 + (double)v1;
    s2 = (double)v0 * (double)v0 + (double)v1 * (double)v1;
  } else if (e0 < EE) {
    int r0 = row[e0], c0 = col[e0];
    float4 a00 = *(const float4*)(Lg + (size_t)r0 * 8);
    float4 a01 = *(const float4*)(Lg + (size_t)r0 * 8 + 4);
    float4 b00 = *(const float4*)(Tg + (size_t)c0 * 8);
    float4 b01 = *(const float4*)(Tg + (size_t)c0 * 8 + 4);
    float v0 = a00.x*b00.x + a00.y*b00.y + a00.z*b00.z + a00.w*b00.w
             + a01.x*b01.x + a01.y*b01.y + a01.z*b01.z + a01.w*b01.w;
    ew_raw[e0] = v0;
    atomicAdd(&cnt[c0], 1);
    atomicAdd(&sraw[c0], v0);
    s = (double)v0; s2 = (double)v0 * (double)v0;
  }
  for (int off = 32; off; off >>= 1) {
    s  += __shfl_down(s, off);
    s2 += __shfl_down(s2, off);
  }
  int wv = threadIdx.x >> 6;
  if ((threadIdx.x & 63) == 0) { shs[wv] = s; shs2[wv] = s2; }
  __syncthreads();
  if (threadIdx.x == 0) {
    part[blockIdx.x]         = shs[0] + shs[1] + shs[2] + shs[3];
    part[NB_E1 + blockIdx.x] = shs2[0] + shs2[1] + shs2[2] + shs2[3];
  }
}

// ---------------- reduce edge1 partials -> red ----------------
__global__ __launch_bounds__(1024)
void redpart_kernel(const double* __restrict__ part, double* __restrict__ red)
{
  __shared__ double sh[16][2];
  int tid = threadIdx.x;
  double s = 0.0, s2 = 0.0;
  for (int i = tid; i < NB_E1; i += 1024) {
    s  += part[i];
    s2 += part[NB_E1 + i];
  }
  for (int off = 32; off; off >>= 1) {
    s  += __shfl_down(s, off);
    s2 += __shfl_down(s2, off);
  }
  if ((tid & 63) == 0) { sh[tid >> 6][0] = s; sh[tid >> 6][1] = s2; }
  __syncthreads();
  if (tid == 0) {
    double a = 0.0, b = 0.0;
    for (int i = 0; i < 16; ++i) { a += sh[i][0]; b += sh[i][1]; }
    red[0] = a; red[1] = b;
  }
}

// ---------------- dinv from raw sums: deg_c = scl*(Sraw_c - cnt_c*mean) + cnt_c ----------------
__global__ __launch_bounds__(256)
void dinv_kernel(const float* __restrict__ sraw, const int* __restrict__ cnt,
                 const double* __restrict__ red, float* __restrict__ dinv)
{
  int n = blockIdx.x * 256 + threadIdx.x;
  if (n >= NN) return;
  double mean = red[0] / (double)EE;
  double var  = (red[1] - (double)EE * mean * mean) / (double)(EE - 1);
  double scl  = sqrt(1e-4 / var);
  double c    = (double)cnt[n];
  double deg  = scl * ((double)sraw[n] - c * mean) + c;
  float d = (float)deg + 1.0f;   // + self-loop weight 1
  dinv[n] = d > 0.f ? 1.0f / sqrtf(fmaxf(d, 1e-12f)) : 0.f;
}

// ---------------- edge pass 2: standardize + CSR fill (src, ew_std*dinv[src]) ----------------
__global__ __launch_bounds__(256)
void edge2_kernel(const int* __restrict__ row, const int* __restrict__ col,
                  const float* __restrict__ ew_raw, const double* __restrict__ red,
                  const int* __restrict__ rowptr, int* __restrict__ cursor,
                  const float* __restrict__ dinv, int2* __restrict__ csr_sw)
{
  int e = blockIdx.x * 256 + threadIdx.x;
  if (e >= EE) return;
  double mean = red[0] / (double)EE;
  double var  = (red[1] - (double)EE * mean * mean) / (double)(EE - 1);
  double scl  = sqrt(1e-4 / var);
  float v = (float)(((double)ew_raw[e] - mean) * scl) + 1.0f;
  int r = row[e], c = col[e];
  float w = v * dinv[r];
  int pos = atomicAdd(&cursor[c], 1);
  int2 sw; sw.x = r; sw.y = __float_as_int(w);
  csr_sw[rowptr[c] + pos] = sw;
}

// ---------------- parallel 3-stage exclusive scan of cnt -> rowptr ----------------
__global__ __launch_bounds__(256)
void scan1_kernel(const int* __restrict__ cnt, int* __restrict__ bsum)
{
  __shared__ int sh[4];
  int i = blockIdx.x * 256 + threadIdx.x;
  int v = (i < NN) ? cnt[i] : 0;
  for (int off = 32; off; off >>= 1) v += __shfl_down(v, off);
  if ((threadIdx.x & 63) == 0) sh[threadIdx.x >> 6] = v;
  __syncthreads();
  if (threadIdx.x == 0) bsum[blockIdx.x] = sh[0] + sh[1] + sh[2] + sh[3];
}

__global__ __launch_bounds__(256)
void scan2_kernel(int* __restrict__ bsum)
{
  __shared__ int sh[256];
  int tid = threadIdx.x;
  int v = (tid < NB_SCAN) ? bsum[tid] : 0;
  sh[tid] = v;
  __syncthreads();
  for (int off = 1; off < 256; off <<= 1) {
    int t = (tid >= off) ? sh[tid - off] : 0;
    __syncthreads();
    sh[tid] += t;
    __syncthreads();
  }
  if (tid < NB_SCAN) bsum[tid] = sh[tid] - v;   // exclusive
}

__global__ __launch_bounds__(256)
void scan3_kernel(const int* __restrict__ cnt, const int* __restrict__ bsum,
                  int* __restrict__ rowptr)
{
  __shared__ int sh[256];
  int tid = threadIdx.x;
  int i = blockIdx.x * 256 + tid;
  int v = (i < NN) ? cnt[i] : 0;
  sh[tid] = v;
  __syncthreads();
  for (int off = 1; off < 256; off <<= 1) {
    int t = (tid >= off) ? sh[tid - off] : 0;
    __syncthreads();
    sh[tid] += t;
    __syncthreads();
  }
  if (i < NN) rowptr[i + 1] = bsum[blockIdx.x] + sh[tid];
  if (i == 0) rowptr[0] = 0;
}

// ---------------- dim-256 aggregation: one node per HALF-WAVE, persistent grid ----
// grid = 1536 == resident capacity at ~76 VGPR (6 blocks/CU). NO min-waves bound:
// launch_bounds(256,6) clamped VGPR->40 and spilled the gather arrays (R11: +340MB
// scratch traffic, 2x slowdown).
#define AGG_ACC(sw_, v_)                                                     \
  {                                                                          \
    float w_ = __int_as_float((sw_).y);                                      \
    a0 += w_ * bf2f((v_)[0]); a1 += w_ * bf2f((v_)[1]);                      \
    a2 += w_ * bf2f((v_)[2]); a3 += w_ * bf2f((v_)[3]);                      \
    a4 += w_ * bf2f((v_)[4]); a5 += w_ * bf2f((v_)[5]);                      \
    a6 += w_ * bf2f((v_)[6]); a7 += w_ * bf2f((v_)[7]);                      \
  }

template<int MODE>
__global__ __launch_bounds__(256)
void agg256_kernel(const int* __restrict__ rowptr, const int2* __restrict__ csr_sw,
                   const unsigned short* __restrict__ gsrc,
                   const float* __restrict__ dinv, const float* __restrict__ bias,
                   const unsigned short* __restrict__ h0in,
                   unsigned short* __restrict__ h0out,
                   unsigned short* __restrict__ xout,
                   const float* __restrict__ w3p, float* __restrict__ y3)
{
  const int tid = threadIdx.x;
  const int hw  = tid >> 5;          // half-wave 0..7
  const int l5  = tid & 31;
  const size_t colbase = (size_t)(l5 << 3);
  const int stride = (int)gridDim.x * 8;

  for (int n = blockIdx.x * 8 + hw; n < NN; n += stride) {
    float a0=0,a1=0,a2=0,a3=0,a4=0,a5=0,a6=0,a7=0;
    const int s = rowptr[n], e = rowptr[n + 1];
    int i = s;
    for (; i + 7 < e; i += 8) {               // 8 gathers in flight
      int2 sw[8];
#pragma unroll
      for (int u = 0; u < 8; ++u) sw[u] = csr_sw[i + u];
      u16x8 v[8];
#pragma unroll
      for (int u = 0; u < 8; ++u) v[u] = *(const u16x8*)(gsrc + (size_t)sw[u].x * 256 + colbase);
#pragma unroll
      for (int u = 0; u < 8; ++u) AGG_ACC(sw[u], v[u])
    }
    for (; i + 3 < e; i += 4) {
      int2 sw[4];
#pragma unroll
      for (int u = 0; u < 4; ++u) sw[u] = csr_sw[i + u];
      u16x8 v[4];
#pragma unroll
      for (int u = 0; u < 4; ++u) v[u] = *(const u16x8*)(gsrc + (size_t)sw[u].x * 256 + colbase);
#pragma unroll
      for (int u = 0; u < 4; ++u) AGG_ACC(sw[u], v[u])
    }
    for (; i < e; ++i) {
      int2 sw = csr_sw[i];
      u16x8 v = *(const u16x8*)(gsrc + (size_t)sw.x * 256 + colbase);
      AGG_ACC(sw, v)
    }
    const int dbase = l5 << 3;
    const float dn = dinv[n];
    const float wd = dn * dn;
    u16x8 sv = *(const u16x8*)(gsrc + (size_t)n * 256 + dbase);
    float4 b0 = *(const float4*)(bias + dbase);
    float4 b1 = *(const float4*)(bias + dbase + 4);
    float f0 = dn * a0 + wd * bf2f(sv[0]) + b0.x;
    float f1 = dn * a1 + wd * bf2f(sv[1]) + b0.y;
    float f2 = dn * a2 + wd * bf2f(sv[2]) + b0.z;
    float f3 = dn * a3 + wd * bf2f(sv[3]) + b0.w;
    float f4 = dn * a4 + wd * bf2f(sv[4]) + b1.x;
    float f5 = dn * a5 + wd * bf2f(sv[5]) + b1.y;
    float f6 = dn * a6 + wd * bf2f(sv[6]) + b1.z;
    float f7 = dn * a7 + wd * bf2f(sv[7]) + b1.w;
    const size_t o = (size_t)n * 256 + dbase;
    if (MODE == 0) {
      u16x8 h;
      h[0] = f2bf(f0); h[1] = f2bf(f1); h[2] = f2bf(f2); h[3] = f2bf(f3);
      h[4] = f2bf(f4); h[5] = f2bf(f5); h[6] = f2bf(f6); h[7] = f2bf(f7);
      *(u16x8*)(h0out + o) = h;
      u16x8 xo;
      xo[0] = f2bf(fmaxf(f0, 0.f)); xo[1] = f2bf(fmaxf(f1, 0.f));
      xo[2] = f2bf(fmaxf(f2, 0.f)); xo[3] = f2bf(fmaxf(f3, 0.f));
      xo[4] = f2bf(fmaxf(f4, 0.f)); xo[5] = f2bf(fmaxf(f5, 0.f));
      xo[6] = f2bf(fmaxf(f6, 0.f)); xo[7] = f2bf(fmaxf(f7, 0.f));
      *(u16x8*)(xout + o) = xo;
    } else {
      u16x8 h = *(const u16x8*)(h0in + o);
      float xv0 = bf2f(f2bf(fmaxf(f0, 0.f) + bf2f(h[0])));
      float xv1 = bf2f(f2bf(fmaxf(f1, 0.f) + bf2f(h[1])));
      float xv2 = bf2f(f2bf(fmaxf(f2, 0.f) + bf2f(h[2])));
      float xv3 = bf2f(f2bf(fmaxf(f3, 0.f) + bf2f(h[3])));
      float xv4 = bf2f(f2bf(fmaxf(f4, 0.f) + bf2f(h[4])));
      float xv5 = bf2f(f2bf(fmaxf(f5, 0.f) + bf2f(h[5])));
      float xv6 = bf2f(f2bf(fmaxf(f6, 0.f) + bf2f(h[6])));
      float xv7 = bf2f(f2bf(fmaxf(f7, 0.f) + bf2f(h[7])));
      const float* w3r = w3p + (size_t)dbase * 8;
      f32x4 p0 = {0,0,0,0}, p1 = {0,0,0,0};
      p0 += xv0 * *(const f32x4*)(w3r +  0); p1 += xv0 * *(const f32x4*)(w3r +  4);
      p0 += xv1 * *(const f32x4*)(w3r +  8); p1 += xv1 * *(const f32x4*)(w3r + 12);
      p0 += xv2 * *(const f32x4*)(w3r + 16); p1 += xv2 * *(const f32x4*)(w3r + 20);
      p0 += xv3 * *(const f32x4*)(w3r + 24); p1 += xv3 * *(const f32x4*)(w3r + 28);
      p0 += xv4 * *(const f32x4*)(w3r + 32); p1 += xv4 * *(const f32x4*)(w3r + 36);
      p0 += xv5 * *(const f32x4*)(w3r + 40); p1 += xv5 * *(const f32x4*)(w3r + 44);
      p0 += xv6 * *(const f32x4*)(w3r + 48); p1 += xv6 * *(const f32x4*)(w3r + 52);
      p0 += xv7 * *(const f32x4*)(w3r + 56); p1 += xv7 * *(const f32x4*)(w3r + 60);
#pragma unroll
      for (int off = 1; off < 32; off <<= 1) {
        p0[0] += __shfl_xor(p0[0], off); p0[1] += __shfl_xor(p0[1], off);
        p0[2] += __shfl_xor(p0[2], off); p0[3] += __shfl_xor(p0[3], off);
        p1[0] += __shfl_xor(p1[0], off); p1[1] += __shfl_xor(p1[1], off);
        p1[2] += __shfl_xor(p1[2], off); p1[3] += __shfl_xor(p1[3], off);
      }
      if (l5 == 0) {
        *(f32x4*)(y3 + (size_t)n * 8)     = p0;
        *(f32x4*)(y3 + (size_t)n * 8 + 4) = p1;
      }
    }
  }
}

// ---------------- dim-7 aggregation: 8 lanes per node, 4-deep ILP ----------------
__global__ __launch_bounds__(256)
void agg7_kernel(const int* __restrict__ rowptr, const int2* __restrict__ csr_sw,
                 const float* __restrict__ y3,
                 const float* __restrict__ dinv, const float* __restrict__ b3,
                 float* __restrict__ out)
{
  int n = blockIdx.x * 32 + (threadIdx.x >> 3);
  if (n >= NN) return;
  int j = threadIdx.x & 7;
  float acc = 0.f;
  int s = rowptr[n], e = rowptr[n + 1];
  int i = s;
  for (; i + 3 < e; i += 4) {
    int2 sw0 = csr_sw[i],     sw1 = csr_sw[i + 1];
    int2 sw2 = csr_sw[i + 2], sw3 = csr_sw[i + 3];
    float v0 = y3[(size_t)sw0.x * 8 + j];
    float v1 = y3[(size_t)sw1.x * 8 + j];
    float v2 = y3[(size_t)sw2.x * 8 + j];
    float v3 = y3[(size_t)sw3.x * 8 + j];
    acc += __int_as_float(sw0.y) * v0 + __int_as_float(sw1.y) * v1
         + __int_as_float(sw2.y) * v2 + __int_as_float(sw3.y) * v3;
  }
  for (; i < e; ++i) {
    int2 sw = csr_sw[i];
    acc += __int_as_float(sw.y) * y3[(size_t)sw.x * 8 + j];
  }
  float dn = dinv[n];
  acc = dn * acc + dn * dn * y3[(size_t)n * 8 + j];
  if (j < 7) out[(size_t)n * 7 + j] = acc + b3[j];
}

// ---------------- host ----------------
extern "C" void kernel_launch(void* const* d_in, const int* in_sizes, int n_in,
                              void* d_out, int out_size, void* d_ws, size_t ws_size,
                              hipStream_t stream)
{
  const float* x   = (const float*)d_in[0];
  const int*   ei  = (const int*)d_in[1];
  const float* W1  = (const float*)d_in[2];
  const float* b1  = (const float*)d_in[3];
  const float* W2  = (const float*)d_in[4];
  const float* b2  = (const float*)d_in[5];
  const float* W3  = (const float*)d_in[6];
  const float* b3  = (const float*)d_in[7];
  const float* mw1 = (const float*)d_in[8];
  const float* mb1 = (const float*)d_in[9];
  const float* mw2 = (const float*)d_in[10];
  const float* mb2 = (const float*)d_in[11];
  const float* mw3 = (const float*)d_in[12];
  const float* mb3 = (const float*)d_in[13];
  const float* par = (const float*)d_in[14];
  const int* row = ei;
  const int* col = ei + EE;
  float* out = (float*)d_out;

  char* ws = (char*)d_ws;
  unsigned short* x_bf  = (unsigned short*)(ws + O_XBF);
  unsigned short* h0    = (unsigned short*)(ws + O_XBF);   // bf16, alias (x_bf dead after fused GEMM)
  unsigned short* h1_bf = (unsigned short*)(ws + O_H1);
  unsigned short* g2_bf = (unsigned short*)(ws + O_H1);    // reuse (h1 dead)
  unsigned short* g1_bf = (unsigned short*)(ws + O_G1);
  unsigned short* x1_bf = (unsigned short*)(ws + O_X1);
  unsigned short* h2_bf = (unsigned short*)(ws + O_H2);
  float* Lg      = (float*)(ws + O_LG);
  float* Tg      = (float*)(ws + O_TG);
  float* ew_raw  = (float*)(ws + O_EWR);
  float* y3      = (float*)(ws + O_EWR);                   // reuse (ew_raw dead after edge2)
  float* w3p     = (float*)(ws + O_W3P);
  int2*  csr_sw  = (int2*)(ws + O_CSR);
  double* part   = (double*)(ws + O_CSR);                  // alias: consumed before edge2 fills csr
  unsigned short* mw1t = (unsigned short*)(ws + O_MW1T);   // fused Bt = [mw1t; w1t], 768 rows
  unsigned short* w1t  = (unsigned short*)(ws + O_W1T);
  unsigned short* w2t  = (unsigned short*)(ws + O_W2T);
  unsigned short* mw2t = (unsigned short*)(ws + O_MW2T);
  float*  sraw   = (float*)(ws + O_SRAW);
  int*    cnt    = (int*)(ws + O_CNT);
  int*    cursor = (int*)(ws + O_CUR);
  double* red    = (double*)(ws + O_RED);
  int*    rowptr = (int*)(ws + O_RPT);
  float*  dinv   = (float*)(ws + O_DINV);
  int*    bsum   = (int*)(ws + O_BSUM);

  // zero: sraw, cnt, cursor (contiguous)
  hipMemsetAsync(ws + O_SRAW, 0, 3 * 200192, stream);

  // fp32 -> bf16 conversions (+ padded W3)
  conv_f2bf4<<<25000, 256, 0, stream>>>(x, x_bf, NN * 512 / 4);
  conv_weights<<<1929, 256, 0, stream>>>(mw1, W1, W2, mw2, W3, mw1t, w1t, w2t, mw2t, w3p);

  // fused MLP1 + GCN1 GEMM
  gemm_fused<<<dim3(6, 391), 256, 0, stream>>>(x_bf, mw1t, mb1, h1_bf, g1_bf, NN);
  // MLP layer 2
  gemm_bf16<true,  true ><<<dim3(1, 391), 256, 0, stream>>>(h1_bf, 512, mw2t, mb2, h2_bf, 64, NN, 64, 512);
  logits_kernel<<<196, 256, 0, stream>>>(h2_bf, mw3, mb3, par, Lg, Tg);

  // edge weights + CSR (deg from raw sums; dinv before edge2; CSR stores final weight)
  edge1_kernel<<<NB_E1, 256, 0, stream>>>(row, col, Lg, Tg, ew_raw, cnt, sraw, part);
  redpart_kernel<<<1, 1024, 0, stream>>>(part, red);
  scan1_kernel<<<NB_SCAN, 256, 0, stream>>>(cnt, bsum);
  scan2_kernel<<<1, 256, 0, stream>>>(bsum);
  scan3_kernel<<<NB_SCAN, 256, 0, stream>>>(cnt, bsum, rowptr);
  dinv_kernel<<<196, 256, 0, stream>>>(sraw, cnt, red, dinv);
  edge2_kernel<<<NB_EDGE, 256, 0, stream>>>(row, col, ew_raw, red, rowptr, cursor, dinv, csr_sw);

  // GCN layer 0 aggregation (persistent, grid == resident capacity at natural VGPR)
  agg256_kernel<0><<<1536, 256, 0, stream>>>(rowptr, csr_sw, g1_bf, dinv, b1, nullptr, h0, x1_bf, nullptr, nullptr);
  // GCN layer 1 (+residual h0), fused with W3 gemv -> y3
  gemm_bf16<false, false><<<dim3(2, 391), 256, 0, stream>>>(x1_bf, 256, w2t, nullptr, g2_bf, 256, NN, 256, 256);
  agg256_kernel<1><<<1536, 256, 0, stream>>>(rowptr, csr_sw, g2_bf, dinv, b2, h0, nullptr, nullptr, w3p, y3);
  // final dim-7 aggregation
  agg7_kernel<<<1563, 256, 0, stream>>>(rowptr, csr_sw, y3, dinv, b3, out);
}

// Round 13
// 419.072 us; speedup vs baseline: 1.2084x; 1.0307x over previous
//
#include <hip/hip_runtime.h>

#define NN 50000
#define EE 800000
#define NB_EDGE 3125   // ceil(EE/256)
#define NB_E1   1563   // ceil(EE/512)
#define NB_SCAN 196    // ceil(NN/256)

typedef __attribute__((ext_vector_type(4))) float f32x4;
typedef __attribute__((ext_vector_type(8))) short bf16x8;
typedef __attribute__((ext_vector_type(8))) unsigned short u16x8;

typedef const __attribute__((address_space(1))) void* gas_p;
typedef __attribute__((address_space(3))) void* las_p;

__device__ __forceinline__ float bf2f(unsigned short u) {
  union { unsigned int i; float f; } v; v.i = ((unsigned int)u) << 16; return v.f;
}
__device__ __forceinline__ unsigned short f2bf(float f) {
  union { float f; unsigned int i; } v; v.f = f;
  unsigned int u = v.i;
  return (unsigned short)((u + 0x7FFFu + ((u >> 16) & 1u)) >> 16);
}

// bijective XCD swizzle (m204)
__device__ __forceinline__ int xcd_swizzle(int orig, int nwg) {
  int xcd = orig & 7;
  int pos = orig >> 3;
  int q = nwg >> 3, r = nwg & 7;
  return (xcd < r ? xcd * (q + 1) : r * (q + 1) + (xcd - r) * q) + pos;
}

// ---------------- workspace layout (bytes, all 256-aligned) ----------------
constexpr size_t O_XBF  = 0;                  // x_bf [50000,512]bf16; reused as h0 [50000,256]bf16
constexpr size_t O_H1   = O_XBF + 51200000;   // h1 [50000,512]bf16; reused as g2
constexpr size_t O_G1   = O_H1  + 51200000;   // g1 [50000,256]bf16
constexpr size_t O_X1   = O_G1  + 25600000;   // x1 [50000,256]bf16
constexpr size_t O_H2   = O_X1  + 25600000;   // h2 [50000,64]bf16
constexpr size_t O_LG   = O_H2  + 6400000;    // Lg [50000,8]f32
constexpr size_t O_TG   = O_LG  + 1600000;    // Tg [50000,8]f32
constexpr size_t O_EWR  = O_TG  + 1600000;    // ew_raw [E]f32; reused as y3 [50000,8]f32
constexpr size_t O_W3P  = O_EWR + 3200000;    // w3p [256][8]f32 (8KB)
constexpr size_t O_CSR  = O_W3P + 3200000;    // csr_sw [E]int2 (aliased: edge1 partials, consumed first)
constexpr size_t O_MW1T = O_CSR + 6400000;    // 512*512 bf16   <- fused Bt starts here
constexpr size_t O_W1T  = O_MW1T + 524288;    // 256*512 bf16   (contiguous: 768 rows total)
constexpr size_t O_W2T  = O_W1T  + 262144;    // 256*256 bf16
constexpr size_t O_MW2T = O_W2T  + 131072;    // 64*512 bf16
constexpr size_t O_CNT  = O_MW2T + 65536;     // [N]i32   <- zero block start
constexpr size_t O_CUR  = O_CNT  + 200192;    // [N]i32   <- zero block end
constexpr size_t O_RED  = O_CUR  + 200192;    // 2 doubles
constexpr size_t O_RPT  = O_RED  + 256;       // [N+1]i32
constexpr size_t O_DINV = O_RPT  + 200192;    // [N]f32
constexpr size_t O_BSUM = O_DINV + 200192;    // [NB_SCAN]i32

// ---------------- conversions ----------------
__global__ __launch_bounds__(256) void conv_f2bf4(const float* __restrict__ in,
                                                  unsigned short* __restrict__ out, int n4) {
  int i = blockIdx.x * 256 + threadIdx.x;
  if (i >= n4) return;
  const float4 v = ((const float4*)in)[i];
  ushort4 o; o.x = f2bf(v.x); o.y = f2bf(v.y); o.z = f2bf(v.z); o.w = f2bf(v.w);
  ((ushort4*)out)[i] = o;
}

__global__ __launch_bounds__(256)
void conv_weights(const float* __restrict__ mw1, const float* __restrict__ W1,
                  const float* __restrict__ W2, const float* __restrict__ mw2,
                  const float* __restrict__ W3,
                  unsigned short* __restrict__ mw1t, unsigned short* __restrict__ w1t,
                  unsigned short* __restrict__ w2t, unsigned short* __restrict__ mw2t,
                  float* __restrict__ w3p)
{
  int i = blockIdx.x * 256 + threadIdx.x;
  if (i < 262144) {                 // mw1: [512,512]
    int k = i >> 9, n = i & 511;
    mw1t[(size_t)n * 512 + k] = f2bf(mw1[i]);
  } else if (i < 393216) {          // W1: [512,256]
    int j = i - 262144, k = j >> 8, n = j & 255;
    w1t[(size_t)n * 512 + k] = f2bf(W1[j]);
  } else if (i < 458752) {          // W2: [256,256]
    int j = i - 393216, k = j >> 8, n = j & 255;
    w2t[(size_t)n * 256 + k] = f2bf(W2[j]);
  } else if (i < 491520) {          // mw2: [512,64]
    int j = i - 458752, k = j >> 6, n = j & 63;
    mw2t[(size_t)n * 512 + k] = f2bf(mw2[j]);
  } else if (i < 493568) {          // W3 pad: [256,7] -> [256,8]
    int j = i - 491520, d = j >> 3, c = j & 7;
    w3p[j] = (c < 7) ? W3[d * 7 + c] : 0.f;
  }
}

// ---------------- GEMM core: 128x128 tile, BK=64, 4 waves, 2-phase dbuf pipeline ----
#define GEMM_STAGE(buf, k0)                                                        \
  _Pragma("unroll")                                                                \
  for (int r = 0; r < 4; ++r) {                                                    \
    const int row = r * 32 + wid * 8 + srow8;                                      \
    int ga = bm + row; ga = ga < M_ ? ga : M_ - 1;                                 \
    int gb = bn + row; gb = gb < N_ ? gb : N_ - 1;                                 \
    __builtin_amdgcn_global_load_lds((gas_p)(pA_ + ((size_t)ga * lda_ + (k0)) * 2 + sks * 16), \
                                     (las_p)(ldsA[buf] + row * 64), 16, 0, 0);     \
    __builtin_amdgcn_global_load_lds((gas_p)(pB_ + ((size_t)gb * ldb_ + (k0)) * 2 + sks * 16), \
                                     (las_p)(ldsB[buf] + row * 64), 16, 0, 0);     \
  }

#define GEMM_BODY(A, lda, Bt, ldb_K, M, Ncols, K, bm, bn)                          \
  __shared__ unsigned short ldsA[2][128 * 64];                                     \
  __shared__ unsigned short ldsB[2][128 * 64];                                     \
  const char* pA_ = (const char*)(A);                                              \
  const char* pB_ = (const char*)(Bt);                                             \
  const int lda_ = (lda), ldb_ = (ldb_K), M_ = (M), N_ = (Ncols);                  \
  const int tid  = threadIdx.x;                                                    \
  const int lane = tid & 63;                                                       \
  const int wid  = tid >> 6;                                                       \
  const int wm   = (wid >> 1) << 6;                                                \
  const int wn   = (wid & 1) << 6;                                                 \
  f32x4 acc[4][4] = {};                                                            \
  const int srow8 = lane >> 3;                                                     \
  const int sks   = (lane & 7) ^ srow8;                                            \
  const int nt    = (K) >> 6;                                                      \
  GEMM_STAGE(0, 0)                                                                 \
  for (int t = 0; t < nt; ++t) {                                                   \
    const int cur = t & 1;                                                         \
    if (t + 1 < nt) {                                                              \
      GEMM_STAGE(cur ^ 1, (t + 1) << 6)                                            \
      asm volatile("s_waitcnt vmcnt(8)" ::: "memory");                             \
    } else {                                                                       \
      asm volatile("s_waitcnt vmcnt(0)" ::: "memory");                             \
    }                                                                              \
    __builtin_amdgcn_s_barrier();                                                  \
    __builtin_amdgcn_sched_barrier(0);                                             \
    const int q   = lane >> 4;                                                     \
    const int r15 = lane & 15;                                                     \
    _Pragma("unroll")                                                              \
    for (int kk = 0; kk < 2; ++kk) {                                               \
      bf16x8 af[4], bfr[4];                                                        \
      _Pragma("unroll")                                                            \
      for (int m = 0; m < 4; ++m) {                                                \
        const int ra = wm + m * 16 + r15;                                          \
        af[m]  = *(const bf16x8*)(ldsA[cur] + ra * 64 + (((kk << 2) + q) ^ (ra & 7)) * 8); \
        const int rb = wn + m * 16 + r15;                                          \
        bfr[m] = *(const bf16x8*)(ldsB[cur] + rb * 64 + (((kk << 2) + q) ^ (rb & 7)) * 8); \
      }                                                                            \
      _Pragma("unroll")                                                            \
      for (int m = 0; m < 4; ++m)                                                  \
        _Pragma("unroll")                                                          \
        for (int n = 0; n < 4; ++n)                                                \
          acc[m][n] = __builtin_amdgcn_mfma_f32_16x16x32_bf16(af[m], bfr[n], acc[m][n], 0, 0, 0); \
    }                                                                              \
    __builtin_amdgcn_sched_barrier(0);                                             \
    __builtin_amdgcn_s_barrier();                                                  \
  }

// ---------------- generic GEMM ----------------
template<bool RELU, bool BIAS>
__global__ __launch_bounds__(256)
void gemm_bf16(const unsigned short* __restrict__ A, int lda,
               const unsigned short* __restrict__ Bt,
               const float* __restrict__ bias,
               unsigned short* __restrict__ C, int ldc,
               int M, int N, int K)
{
  const int nwg  = gridDim.x * gridDim.y;
  const int wgid = xcd_swizzle(blockIdx.y * gridDim.x + blockIdx.x, nwg);
  const int bn   = (wgid % gridDim.x) << 7;
  const int bm   = (wgid / gridDim.x) << 7;

  GEMM_BODY(A, lda, Bt, K, M, N, K, bm, bn)

  const int q   = lane >> 4;
  const int r15 = lane & 15;
#pragma unroll
  for (int m = 0; m < 4; ++m) {
#pragma unroll
    for (int n = 0; n < 4; ++n) {
      const int gc = bn + wn + n * 16 + r15;
#pragma unroll
      for (int i = 0; i < 4; ++i) {
        const int gr = bm + wm + m * 16 + q * 4 + i;
        if (gr < M && gc < N) {
          float f = acc[m][n][i];
          if (BIAS) f += bias[gc];
          if (RELU) f = fmaxf(f, 0.f);
          C[(size_t)gr * ldc + gc] = f2bf(f);
        }
      }
    }
  }
}

// ---------------- fused MLP1+GCN1 GEMM: A=x_bf [M,512], Bt=[768,512] ----------------
__global__ __launch_bounds__(256)
void gemm_fused(const unsigned short* __restrict__ A,
                const unsigned short* __restrict__ Bt,
                const float* __restrict__ mb1,
                unsigned short* __restrict__ h1,
                unsigned short* __restrict__ g1,
                int M)
{
  const int nwg  = gridDim.x * gridDim.y;
  const int wgid = xcd_swizzle(blockIdx.y * gridDim.x + blockIdx.x, nwg);
  const int bnt  = wgid % gridDim.x;
  const int bn   = bnt << 7;
  const int bm   = (wgid / gridDim.x) << 7;

  GEMM_BODY(A, 512, Bt, 512, M, 768, 512, bm, bn)

  const int q   = lane >> 4;
  const int r15 = lane & 15;
  if (bnt < 4) {   // h1: bias + relu
#pragma unroll
    for (int m = 0; m < 4; ++m) {
#pragma unroll
      for (int n = 0; n < 4; ++n) {
        const int gc = bn + wn + n * 16 + r15;
        const float b = mb1[gc];
#pragma unroll
        for (int i = 0; i < 4; ++i) {
          const int gr = bm + wm + m * 16 + q * 4 + i;
          if (gr < M) h1[(size_t)gr * 512 + gc] = f2bf(fmaxf(acc[m][n][i] + b, 0.f));
        }
      }
    }
  } else {         // g1: plain
#pragma unroll
    for (int m = 0; m < 4; ++m) {
#pragma unroll
      for (int n = 0; n < 4; ++n) {
        const int gc = bn - 512 + wn + n * 16 + r15;
#pragma unroll
        for (int i = 0; i < 4; ++i) {
          const int gr = bm + wm + m * 16 + q * 4 + i;
          if (gr < M) g1[(size_t)gr * 256 + gc] = f2bf(acc[m][n][i]);
        }
      }
    }
  }
}

// ---------------- logits ----------------
__global__ __launch_bounds__(256)
void logits_kernel(const unsigned short* __restrict__ h2, const float* __restrict__ mw3,
                   const float* __restrict__ mb3, const float* __restrict__ par,
                   float* __restrict__ Lg, float* __restrict__ Tg)
{
  __shared__ float w[64 * 8];
  __shared__ float P[64];
  int tid = threadIdx.x;
  for (int i = tid; i < 512; i += 256) {
    int k = i >> 3, c = i & 7;
    w[i] = (c < 7) ? mw3[k * 7 + c] : 0.f;
  }
  if (tid < 64) {
    int d = tid >> 3, c = tid & 7;
    P[tid] = (d < 7 && c < 7) ? fmaxf(2.0f * par[d * 7 + c], 0.f) : 0.f;
  }
  __syncthreads();
  int n = blockIdx.x * 256 + tid;
  if (n >= NN) return;
  const unsigned short* hr = h2 + (size_t)n * 64;
  f32x4 L0 = {0,0,0,0}, L1 = {0,0,0,0};
  for (int k = 0; k < 64; k += 4) {
    ushort4 v = *(const ushort4*)(hr + k);
    float xs[4] = {bf2f(v.x), bf2f(v.y), bf2f(v.z), bf2f(v.w)};
#pragma unroll
    for (int j = 0; j < 4; ++j) {
      L0 += xs[j] * *(const f32x4*)&w[(k + j) * 8];
      L1 += xs[j] * *(const f32x4*)&w[(k + j) * 8 + 4];
    }
  }
  float Ls[8] = {L0[0], L0[1], L0[2], L0[3], L1[0], L1[1], L1[2], 0.f};
#pragma unroll
  for (int c = 0; c < 7; ++c) Ls[c] += mb3[c];
  f32x4 T0 = {0,0,0,0}, T1 = {0,0,0,0};
#pragma unroll
  for (int d = 0; d < 7; ++d) {
    T0 += Ls[d] * *(const f32x4*)&P[d * 8];
    T1 += Ls[d] * *(const f32x4*)&P[d * 8 + 4];
  }
  f32x4 o0 = {Ls[0], Ls[1], Ls[2], Ls[3]};
  f32x4 o1 = {Ls[4], Ls[5], Ls[6], 0.f};
  *(f32x4*)(Lg + (size_t)n * 8)     = o0;
  *(f32x4*)(Lg + (size_t)n * 8 + 4) = o1;
  *(f32x4*)(Tg + (size_t)n * 8)     = T0;
  *(f32x4*)(Tg + (size_t)n * 8 + 4) = T1;
}

// ---------------- edge pass 1: 2 edges/thread; raw ew + cnt histogram + partials ----
// (cnt atomics only -- R12 lesson: the extra per-edge sraw float atomics doubled
//  the atomic count and made edge1 the top kernel at 78us / 1% VALUBusy)
__global__ __launch_bounds__(256)
void edge1_kernel(const int* __restrict__ row, const int* __restrict__ col,
                  const float* __restrict__ Lg, const float* __restrict__ Tg,
                  float* __restrict__ ew_raw, int* __restrict__ cnt,
                  double* __restrict__ part)
{
  __shared__ double shs[4], shs2[4];
  const int e0 = blockIdx.x * 512 + threadIdx.x;
  const int e1 = e0 + 256;
  double s = 0.0, s2 = 0.0;
  if (e1 < EE) {
    int r0 = row[e0], c0 = col[e0];
    int r1 = row[e1], c1 = col[e1];
    float4 a00 = *(const float4*)(Lg + (size_t)r0 * 8);
    float4 a01 = *(const float4*)(Lg + (size_t)r0 * 8 + 4);
    float4 a10 = *(const float4*)(Lg + (size_t)r1 * 8);
    float4 a11 = *(const float4*)(Lg + (size_t)r1 * 8 + 4);
    float4 b00 = *(const float4*)(Tg + (size_t)c0 * 8);
    float4 b01 = *(const float4*)(Tg + (size_t)c0 * 8 + 4);
    float4 b10 = *(const float4*)(Tg + (size_t)c1 * 8);
    float4 b11 = *(const float4*)(Tg + (size_t)c1 * 8 + 4);
    float v0 = a00.x*b00.x + a00.y*b00.y + a00.z*b00.z + a00.w*b00.w
             + a01.x*b01.x + a01.y*b01.y + a01.z*b01.z + a01.w*b01.w;
    float v1 = a10.x*b10.x + a10.y*b10.y + a10.z*b10.z + a10.w*b10.w
             + a11.x*b11.x + a11.y*b11.y + a11.z*b11.z + a11.w*b11.w;
    ew_raw[e0] = v0; ew_raw[e1] = v1;
    atomicAdd(&cnt[c0], 1); atomicAdd(&cnt[c1], 1);
    s = (double)v0 + (double)v1;
    s2 = (double)v0 * (double)v0 + (double)v1 * (double)v1;
  } else if (e0 < EE) {
    int r0 = row[e0], c0 = col[e0];
    float4 a00 = *(const float4*)(Lg + (size_t)r0 * 8);
    float4 a01 = *(const float4*)(Lg + (size_t)r0 * 8 + 4);
    float4 b00 = *(const float4*)(Tg + (size_t)c0 * 8);
    float4 b01 = *(const float4*)(Tg + (size_t)c0 * 8 + 4);
    float v0 = a00.x*b00.x + a00.y*b00.y + a00.z*b00.z + a00.w*b00.w
             + a01.x*b01.x + a01.y*b01.y + a01.z*b01.z + a01.w*b01.w;
    ew_raw[e0] = v0;
    atomicAdd(&cnt[c0], 1);
    s = (double)v0; s2 = (double)v0 * (double)v0;
  }
  for (int off = 32; off; off >>= 1) {
    s  += __shfl_down(s, off);
    s2 += __shfl_down(s2, off);
  }
  int wv = threadIdx.x >> 6;
  if ((threadIdx.x & 63) == 0) { shs[wv] = s; shs2[wv] = s2; }
  __syncthreads();
  if (threadIdx.x == 0) {
    part[blockIdx.x]         = shs[0] + shs[1] + shs[2] + shs[3];
    part[NB_E1 + blockIdx.x] = shs2[0] + shs2[1] + shs2[2] + shs2[3];
  }
}

// ---------------- reduce edge1 partials -> red ----------------
__global__ __launch_bounds__(1024)
void redpart_kernel(const double* __restrict__ part, double* __restrict__ red)
{
  __shared__ double sh[16][2];
  int tid = threadIdx.x;
  double s = 0.0, s2 = 0.0;
  for (int i = tid; i < NB_E1; i += 1024) {
    s  += part[i];
    s2 += part[NB_E1 + i];
  }
  for (int off = 32; off; off >>= 1) {
    s  += __shfl_down(s, off);
    s2 += __shfl_down(s2, off);
  }
  if ((tid & 63) == 0) { sh[tid >> 6][0] = s; sh[tid >> 6][1] = s2; }
  __syncthreads();
  if (tid == 0) {
    double a = 0.0, b = 0.0;
    for (int i = 0; i < 16; ++i) { a += sh[i][0]; b += sh[i][1]; }
    red[0] = a; red[1] = b;
  }
}

// ---------------- edge pass 2: standardize + CSR fill (src, ew_std) ----------------
__global__ __launch_bounds__(256)
void edge2_kernel(const int* __restrict__ row, const int* __restrict__ col,
                  const float* __restrict__ ew_raw, const double* __restrict__ red,
                  const int* __restrict__ rowptr, int* __restrict__ cursor,
                  int2* __restrict__ csr_sw)
{
  int e = blockIdx.x * 256 + threadIdx.x;
  if (e >= EE) return;
  double mean = red[0] / (double)EE;
  double var  = (red[1] - (double)EE * mean * mean) / (double)(EE - 1);
  double scl  = sqrt(1e-4 / var);
  float v = (float)(((double)ew_raw[e] - mean) * scl) + 1.0f;
  int r = row[e], c = col[e];
  int pos = atomicAdd(&cursor[c], 1);
  int2 sw; sw.x = r; sw.y = __float_as_int(v);
  csr_sw[rowptr[c] + pos] = sw;
}

// ---------------- deg from CSR rows (no atomics) + dinv ----------------
__global__ __launch_bounds__(256)
void degdinv_kernel(const int* __restrict__ rowptr, const int2* __restrict__ csr_sw,
                    float* __restrict__ dinv)
{
  int n = blockIdx.x * 256 + threadIdx.x;
  if (n >= NN) return;
  int s = rowptr[n], e = rowptr[n + 1];
  float deg = 0.f;
  for (int i = s; i < e; ++i) deg += __int_as_float(csr_sw[i].y);
  float d = deg + 1.0f;   // + self-loop weight 1
  dinv[n] = d > 0.f ? 1.0f / sqrtf(fmaxf(d, 1e-12f)) : 0.f;
}

// ---------------- scale csr weights by dinv[src] (coalesced) ----------------
__global__ __launch_bounds__(256)
void scale_csr_kernel(int2* __restrict__ csr_sw, const float* __restrict__ dinv)
{
  int i = blockIdx.x * 256 + threadIdx.x;
  if (i >= EE) return;
  int2 sw = csr_sw[i];
  sw.y = __float_as_int(__int_as_float(sw.y) * dinv[sw.x]);
  csr_sw[i] = sw;
}

// ---------------- parallel 3-stage exclusive scan of cnt -> rowptr ----------------
__global__ __launch_bounds__(256)
void scan1_kernel(const int* __restrict__ cnt, int* __restrict__ bsum)
{
  __shared__ int sh[4];
  int i = blockIdx.x * 256 + threadIdx.x;
  int v = (i < NN) ? cnt[i] : 0;
  for (int off = 32; off; off >>= 1) v += __shfl_down(v, off);
  if ((threadIdx.x & 63) == 0) sh[threadIdx.x >> 6] = v;
  __syncthreads();
  if (threadIdx.x == 0) bsum[blockIdx.x] = sh[0] + sh[1] + sh[2] + sh[3];
}

__global__ __launch_bounds__(256)
void scan2_kernel(int* __restrict__ bsum)
{
  __shared__ int sh[256];
  int tid = threadIdx.x;
  int v = (tid < NB_SCAN) ? bsum[tid] : 0;
  sh[tid] = v;
  __syncthreads();
  for (int off = 1; off < 256; off <<= 1) {
    int t = (tid >= off) ? sh[tid - off] : 0;
    __syncthreads();
    sh[tid] += t;
    __syncthreads();
  }
  if (tid < NB_SCAN) bsum[tid] = sh[tid] - v;   // exclusive
}

__global__ __launch_bounds__(256)
void scan3_kernel(const int* __restrict__ cnt, const int* __restrict__ bsum,
                  int* __restrict__ rowptr)
{
  __shared__ int sh[256];
  int tid = threadIdx.x;
  int i = blockIdx.x * 256 + tid;
  int v = (i < NN) ? cnt[i] : 0;
  sh[tid] = v;
  __syncthreads();
  for (int off = 1; off < 256; off <<= 1) {
    int t = (tid >= off) ? sh[tid - off] : 0;
    __syncthreads();
    sh[tid] += t;
    __syncthreads();
  }
  if (i < NN) rowptr[i + 1] = bsum[blockIdx.x] + sh[tid];
  if (i == 0) rowptr[0] = 0;
}

// ---------------- dim-256 aggregation: one node per HALF-WAVE, persistent grid ----
// grid = 1536 == resident capacity at ~76 VGPR (6 blocks/CU). NO min-waves bound:
// launch_bounds(256,6) clamped VGPR->40 and spilled the gather arrays (R11).
#define AGG_ACC(sw_, v_)                                                     \
  {                                                                          \
    float w_ = __int_as_float((sw_).y);                                      \
    a0 += w_ * bf2f((v_)[0]); a1 += w_ * bf2f((v_)[1]);                      \
    a2 += w_ * bf2f((v_)[2]); a3 += w_ * bf2f((v_)[3]);                      \
    a4 += w_ * bf2f((v_)[4]); a5 += w_ * bf2f((v_)[5]);                      \
    a6 += w_ * bf2f((v_)[6]); a7 += w_ * bf2f((v_)[7]);                      \
  }

template<int MODE>
__global__ __launch_bounds__(256)
void agg256_kernel(const int* __restrict__ rowptr, const int2* __restrict__ csr_sw,
                   const unsigned short* __restrict__ gsrc,
                   const float* __restrict__ dinv, const float* __restrict__ bias,
                   const unsigned short* __restrict__ h0in,
                   unsigned short* __restrict__ h0out,
                   unsigned short* __restrict__ xout,
                   const float* __restrict__ w3p, float* __restrict__ y3)
{
  const int tid = threadIdx.x;
  const int hw  = tid >> 5;          // half-wave 0..7
  const int l5  = tid & 31;
  const size_t colbase = (size_t)(l5 << 3);
  const int stride = (int)gridDim.x * 8;

  for (int n = blockIdx.x * 8 + hw; n < NN; n += stride) {
    float a0=0,a1=0,a2=0,a3=0,a4=0,a5=0,a6=0,a7=0;
    const int s = rowptr[n], e = rowptr[n + 1];
    int i = s;
    for (; i + 7 < e; i += 8) {               // 8 gathers in flight
      int2 sw[8];
#pragma unroll
      for (int u = 0; u < 8; ++u) sw[u] = csr_sw[i + u];
      u16x8 v[8];
#pragma unroll
      for (int u = 0; u < 8; ++u) v[u] = *(const u16x8*)(gsrc + (size_t)sw[u].x * 256 + colbase);
#pragma unroll
      for (int u = 0; u < 8; ++u) AGG_ACC(sw[u], v[u])
    }
    for (; i + 3 < e; i += 4) {
      int2 sw[4];
#pragma unroll
      for (int u = 0; u < 4; ++u) sw[u] = csr_sw[i + u];
      u16x8 v[4];
#pragma unroll
      for (int u = 0; u < 4; ++u) v[u] = *(const u16x8*)(gsrc + (size_t)sw[u].x * 256 + colbase);
#pragma unroll
      for (int u = 0; u < 4; ++u) AGG_ACC(sw[u], v[u])
    }
    for (; i < e; ++i) {
      int2 sw = csr_sw[i];
      u16x8 v = *(const u16x8*)(gsrc + (size_t)sw.x * 256 + colbase);
      AGG_ACC(sw, v)
    }
    const int dbase = l5 << 3;
    const float dn = dinv[n];
    const float wd = dn * dn;
    u16x8 sv = *(const u16x8*)(gsrc + (size_t)n * 256 + dbase);
    float4 b0 = *(const float4*)(bias + dbase);
    float4 b1 = *(const float4*)(bias + dbase + 4);
    float f0 = dn * a0 + wd * bf2f(sv[0]) + b0.x;
    float f1 = dn * a1 + wd * bf2f(sv[1]) + b0.y;
    float f2 = dn * a2 + wd * bf2f(sv[2]) + b0.z;
    float f3 = dn * a3 + wd * bf2f(sv[3]) + b0.w;
    float f4 = dn * a4 + wd * bf2f(sv[4]) + b1.x;
    float f5 = dn * a5 + wd * bf2f(sv[5]) + b1.y;
    float f6 = dn * a6 + wd * bf2f(sv[6]) + b1.z;
    float f7 = dn * a7 + wd * bf2f(sv[7]) + b1.w;
    const size_t o = (size_t)n * 256 + dbase;
    if (MODE == 0) {
      u16x8 h;
      h[0] = f2bf(f0); h[1] = f2bf(f1); h[2] = f2bf(f2); h[3] = f2bf(f3);
      h[4] = f2bf(f4); h[5] = f2bf(f5); h[6] = f2bf(f6); h[7] = f2bf(f7);
      *(u16x8*)(h0out + o) = h;
      u16x8 xo;
      xo[0] = f2bf(fmaxf(f0, 0.f)); xo[1] = f2bf(fmaxf(f1, 0.f));
      xo[2] = f2bf(fmaxf(f2, 0.f)); xo[3] = f2bf(fmaxf(f3, 0.f));
      xo[4] = f2bf(fmaxf(f4, 0.f)); xo[5] = f2bf(fmaxf(f5, 0.f));
      xo[6] = f2bf(fmaxf(f6, 0.f)); xo[7] = f2bf(fmaxf(f7, 0.f));
      *(u16x8*)(xout + o) = xo;
    } else {
      u16x8 h = *(const u16x8*)(h0in + o);
      float xv0 = bf2f(f2bf(fmaxf(f0, 0.f) + bf2f(h[0])));
      float xv1 = bf2f(f2bf(fmaxf(f1, 0.f) + bf2f(h[1])));
      float xv2 = bf2f(f2bf(fmaxf(f2, 0.f) + bf2f(h[2])));
      float xv3 = bf2f(f2bf(fmaxf(f3, 0.f) + bf2f(h[3])));
      float xv4 = bf2f(f2bf(fmaxf(f4, 0.f) + bf2f(h[4])));
      float xv5 = bf2f(f2bf(fmaxf(f5, 0.f) + bf2f(h[5])));
      float xv6 = bf2f(f2bf(fmaxf(f6, 0.f) + bf2f(h[6])));
      float xv7 = bf2f(f2bf(fmaxf(f7, 0.f) + bf2f(h[7])));
      const float* w3r = w3p + (size_t)dbase * 8;
      f32x4 p0 = {0,0,0,0}, p1 = {0,0,0,0};
      p0 += xv0 * *(const f32x4*)(w3r +  0); p1 += xv0 * *(const f32x4*)(w3r +  4);
      p0 += xv1 * *(const f32x4*)(w3r +  8); p1 += xv1 * *(const f32x4*)(w3r + 12);
      p0 += xv2 * *(const f32x4*)(w3r + 16); p1 += xv2 * *(const f32x4*)(w3r + 20);
      p0 += xv3 * *(const f32x4*)(w3r + 24); p1 += xv3 * *(const f32x4*)(w3r + 28);
      p0 += xv4 * *(const f32x4*)(w3r + 32); p1 += xv4 * *(const f32x4*)(w3r + 36);
      p0 += xv5 * *(const f32x4*)(w3r + 40); p1 += xv5 * *(const f32x4*)(w3r + 44);
      p0 += xv6 * *(const f32x4*)(w3r + 48); p1 += xv6 * *(const f32x4*)(w3r + 52);
      p0 += xv7 * *(const f32x4*)(w3r + 56); p1 += xv7 * *(const f32x4*)(w3r + 60);
#pragma unroll
      for (int off = 1; off < 32; off <<= 1) {
        p0[0] += __shfl_xor(p0[0], off); p0[1] += __shfl_xor(p0[1], off);
        p0[2] += __shfl_xor(p0[2], off); p0[3] += __shfl_xor(p0[3], off);
        p1[0] += __shfl_xor(p1[0], off); p1[1] += __shfl_xor(p1[1], off);
        p1[2] += __shfl_xor(p1[2], off); p1[3] += __shfl_xor(p1[3], off);
      }
      if (l5 == 0) {
        *(f32x4*)(y3 + (size_t)n * 8)     = p0;
        *(f32x4*)(y3 + (size_t)n * 8 + 4) = p1;
      }
    }
  }
}

// ---------------- dim-7 aggregation: 8 lanes per node, 4-deep ILP ----------------
__global__ __launch_bounds__(256)
void agg7_kernel(const int* __restrict__ rowptr, const int2* __restrict__ csr_sw,
                 const float* __restrict__ y3,
                 const float* __restrict__ dinv, const float* __restrict__ b3,
                 float* __restrict__ out)
{
  int n = blockIdx.x * 32 + (threadIdx.x >> 3);
  if (n >= NN) return;
  int j = threadIdx.x & 7;
  float acc = 0.f;
  int s = rowptr[n], e = rowptr[n + 1];
  int i = s;
  for (; i + 3 < e; i += 4) {
    int2 sw0 = csr_sw[i],     sw1 = csr_sw[i + 1];
    int2 sw2 = csr_sw[i + 2], sw3 = csr_sw[i + 3];
    float v0 = y3[(size_t)sw0.x * 8 + j];
    float v1 = y3[(size_t)sw1.x * 8 + j];
    float v2 = y3[(size_t)sw2.x * 8 + j];
    float v3 = y3[(size_t)sw3.x * 8 + j];
    acc += __int_as_float(sw0.y) * v0 + __int_as_float(sw1.y) * v1
         + __int_as_float(sw2.y) * v2 + __int_as_float(sw3.y) * v3;
  }
  for (; i < e; ++i) {
    int2 sw = csr_sw[i];
    acc += __int_as_float(sw.y) * y3[(size_t)sw.x * 8 + j];
  }
  float dn = dinv[n];
  acc = dn * acc + dn * dn * y3[(size_t)n * 8 + j];
  if (j < 7) out[(size_t)n * 7 + j] = acc + b3[j];
}

// ---------------- host ----------------
extern "C" void kernel_launch(void* const* d_in, const int* in_sizes, int n_in,
                              void* d_out, int out_size, void* d_ws, size_t ws_size,
                              hipStream_t stream)
{
  const float* x   = (const float*)d_in[0];
  const int*   ei  = (const int*)d_in[1];
  const float* W1  = (const float*)d_in[2];
  const float* b1  = (const float*)d_in[3];
  const float* W2  = (const float*)d_in[4];
  const float* b2  = (const float*)d_in[5];
  const float* W3  = (const float*)d_in[6];
  const float* b3  = (const float*)d_in[7];
  const float* mw1 = (const float*)d_in[8];
  const float* mb1 = (const float*)d_in[9];
  const float* mw2 = (const float*)d_in[10];
  const float* mb2 = (const float*)d_in[11];
  const float* mw3 = (const float*)d_in[12];
  const float* mb3 = (const float*)d_in[13];
  const float* par = (const float*)d_in[14];
  const int* row = ei;
  const int* col = ei + EE;
  float* out = (float*)d_out;

  char* ws = (char*)d_ws;
  unsigned short* x_bf  = (unsigned short*)(ws + O_XBF);
  unsigned short* h0    = (unsigned short*)(ws + O_XBF);   // bf16, alias (x_bf dead after fused GEMM)
  unsigned short* h1_bf = (unsigned short*)(ws + O_H1);
  unsigned short* g2_bf = (unsigned short*)(ws + O_H1);    // reuse (h1 dead)
  unsigned short* g1_bf = (unsigned short*)(ws + O_G1);
  unsigned short* x1_bf = (unsigned short*)(ws + O_X1);
  unsigned short* h2_bf = (unsigned short*)(ws + O_H2);
  float* Lg      = (float*)(ws + O_LG);
  float* Tg      = (float*)(ws + O_TG);
  float* ew_raw  = (float*)(ws + O_EWR);
  float* y3      = (float*)(ws + O_EWR);                   // reuse (ew_raw dead after edge2)
  float* w3p     = (float*)(ws + O_W3P);
  int2*  csr_sw  = (int2*)(ws + O_CSR);
  double* part   = (double*)(ws + O_CSR);                  // alias: consumed before edge2 fills csr
  unsigned short* mw1t = (unsigned short*)(ws + O_MW1T);   // fused Bt = [mw1t; w1t], 768 rows
  unsigned short* w1t  = (unsigned short*)(ws + O_W1T);
  unsigned short* w2t  = (unsigned short*)(ws + O_W2T);
  unsigned short* mw2t = (unsigned short*)(ws + O_MW2T);
  int*    cnt    = (int*)(ws + O_CNT);
  int*    cursor = (int*)(ws + O_CUR);
  double* red    = (double*)(ws + O_RED);
  int*    rowptr = (int*)(ws + O_RPT);
  float*  dinv   = (float*)(ws + O_DINV);
  int*    bsum   = (int*)(ws + O_BSUM);

  // zero: cnt, cursor (contiguous)
  hipMemsetAsync(ws + O_CNT, 0, 2 * 200192, stream);

  // fp32 -> bf16 conversions (+ padded W3)
  conv_f2bf4<<<25000, 256, 0, stream>>>(x, x_bf, NN * 512 / 4);
  conv_weights<<<1929, 256, 0, stream>>>(mw1, W1, W2, mw2, W3, mw1t, w1t, w2t, mw2t, w3p);

  // fused MLP1 + GCN1 GEMM
  gemm_fused<<<dim3(6, 391), 256, 0, stream>>>(x_bf, mw1t, mb1, h1_bf, g1_bf, NN);
  // MLP layer 2
  gemm_bf16<true,  true ><<<dim3(1, 391), 256, 0, stream>>>(h1_bf, 512, mw2t, mb2, h2_bf, 64, NN, 64, 512);
  logits_kernel<<<196, 256, 0, stream>>>(h2_bf, mw3, mb3, par, Lg, Tg);

  // edge weights + CSR (cnt-only atomics; deg summed from CSR; then scale by dinv[src])
  edge1_kernel<<<NB_E1, 256, 0, stream>>>(row, col, Lg, Tg, ew_raw, cnt, part);
  redpart_kernel<<<1, 1024, 0, stream>>>(part, red);
  scan1_kernel<<<NB_SCAN, 256, 0, stream>>>(cnt, bsum);
  scan2_kernel<<<1, 256, 0, stream>>>(bsum);
  scan3_kernel<<<NB_SCAN, 256, 0, stream>>>(cnt, bsum, rowptr);
  edge2_kernel<<<NB_EDGE, 256, 0, stream>>>(row, col, ew_raw, red, rowptr, cursor, csr_sw);
  degdinv_kernel<<<196, 256, 0, stream>>>(rowptr, csr_sw, dinv);
  scale_csr_kernel<<<NB_EDGE, 256, 0, stream>>>(csr_sw, dinv);

  // GCN layer 0 aggregation (persistent, grid == resident capacity at natural VGPR)
  agg256_kernel<0><<<1536, 256, 0, stream>>>(rowptr, csr_sw, g1_bf, dinv, b1, nullptr, h0, x1_bf, nullptr, nullptr);
  // GCN layer 1 (+residual h0), fused with W3 gemv -> y3
  gemm_bf16<false, false><<<dim3(2, 391), 256, 0, stream>>>(x1_bf, 256, w2t, nullptr, g2_bf, 256, NN, 256, 256);
  agg256_kernel<1><<<1536, 256, 0, stream>>>(rowptr, csr_sw, g2_bf, dinv, b2, h0, nullptr, nullptr, w3p, y3);
  // final dim-7 aggregation
  agg7_kernel<<<1563, 256, 0, stream>>>(rowptr, csr_sw, y3, dinv, b3, out);
}

// Round 14
// 377.185 us; speedup vs baseline: 1.3426x; 1.1111x over previous
//
#include <hip/hip_runtime.h>

#define NN 50000
#define EE 800000
#define NB_EDGE 3125   // ceil(EE/256)
#define NB_E1   1563   // ceil(EE/512)
#define NB_SCAN 196    // ceil(NN/256)

typedef __attribute__((ext_vector_type(4))) float f32x4;
typedef __attribute__((ext_vector_type(8))) short bf16x8;
typedef __attribute__((ext_vector_type(8))) unsigned short u16x8;

typedef const __attribute__((address_space(1))) void* gas_p;
typedef __attribute__((address_space(3))) void* las_p;

__device__ __forceinline__ float bf2f(unsigned short u) {
  union { unsigned int i; float f; } v; v.i = ((unsigned int)u) << 16; return v.f;
}
__device__ __forceinline__ unsigned short f2bf(float f) {
  union { float f; unsigned int i; } v; v.f = f;
  unsigned int u = v.i;
  return (unsigned short)((u + 0x7FFFu + ((u >> 16) & 1u)) >> 16);
}

// bijective XCD swizzle (m204)
__device__ __forceinline__ int xcd_swizzle(int orig, int nwg) {
  int xcd = orig & 7;
  int pos = orig >> 3;
  int q = nwg >> 3, r = nwg & 7;
  return (xcd < r ? xcd * (q + 1) : r * (q + 1) + (xcd - r) * q) + pos;
}

// ---------------- workspace layout (bytes, all 256-aligned) ----------------
constexpr size_t O_XBF  = 0;                  // x_bf [50000,512]bf16; reused as h0 [50000,256]bf16
constexpr size_t O_H1   = O_XBF + 51200000;   // h1 [50000,512]bf16; reused as g2
constexpr size_t O_G1   = O_H1  + 51200000;   // g1 [50000,256]bf16
constexpr size_t O_X1   = O_G1  + 25600000;   // x1 [50000,256]bf16
constexpr size_t O_H2   = O_X1  + 25600000;   // h2 [50000,64]bf16
constexpr size_t O_LG   = O_H2  + 6400000;    // Lg [50000,8]f32
constexpr size_t O_TG   = O_LG  + 1600000;    // Tg [50000,8]f32
constexpr size_t O_EWR  = O_TG  + 1600000;    // ew_raw [E]f32; reused as y3 [50000,8]f32
constexpr size_t O_W3P  = O_EWR + 3200000;    // w3p [256][8]f32 (8KB) + rk [E]u16 (1.6MB)
constexpr size_t O_RK   = O_W3P + 8192;       // rk [E]u16
constexpr size_t O_CSR  = O_W3P + 3200000;    // csr_sw [E]int2 (aliased: edge1 partials, consumed first)
constexpr size_t O_MW1T = O_CSR + 6400000;    // 512*512 bf16   <- fused Bt starts here
constexpr size_t O_W1T  = O_MW1T + 524288;    // 256*512 bf16   (contiguous: 768 rows total)
constexpr size_t O_W2T  = O_W1T  + 262144;    // 256*256 bf16
constexpr size_t O_MW2T = O_W2T  + 131072;    // 64*512 bf16
constexpr size_t O_CNT  = O_MW2T + 65536;     // [N]i32   <- zeroed
constexpr size_t O_RED  = O_CNT  + 200192;    // 2 doubles
constexpr size_t O_RPT  = O_RED  + 256;       // [N+1]i32
constexpr size_t O_DINV = O_RPT  + 200192;    // [N]f32
constexpr size_t O_BSUM = O_DINV + 200192;    // [NB_SCAN]i32

// ---------------- conversions ----------------
__global__ __launch_bounds__(256) void conv_f2bf4(const float* __restrict__ in,
                                                  unsigned short* __restrict__ out, int n4) {
  int i = blockIdx.x * 256 + threadIdx.x;
  if (i >= n4) return;
  const float4 v = ((const float4*)in)[i];
  ushort4 o; o.x = f2bf(v.x); o.y = f2bf(v.y); o.z = f2bf(v.z); o.w = f2bf(v.w);
  ((ushort4*)out)[i] = o;
}

__global__ __launch_bounds__(256)
void conv_weights(const float* __restrict__ mw1, const float* __restrict__ W1,
                  const float* __restrict__ W2, const float* __restrict__ mw2,
                  const float* __restrict__ W3,
                  unsigned short* __restrict__ mw1t, unsigned short* __restrict__ w1t,
                  unsigned short* __restrict__ w2t, unsigned short* __restrict__ mw2t,
                  float* __restrict__ w3p)
{
  int i = blockIdx.x * 256 + threadIdx.x;
  if (i < 262144) {                 // mw1: [512,512]
    int k = i >> 9, n = i & 511;
    mw1t[(size_t)n * 512 + k] = f2bf(mw1[i]);
  } else if (i < 393216) {          // W1: [512,256]
    int j = i - 262144, k = j >> 8, n = j & 255;
    w1t[(size_t)n * 512 + k] = f2bf(W1[j]);
  } else if (i < 458752) {          // W2: [256,256]
    int j = i - 393216, k = j >> 8, n = j & 255;
    w2t[(size_t)n * 256 + k] = f2bf(W2[j]);
  } else if (i < 491520) {          // mw2: [512,64]
    int j = i - 458752, k = j >> 6, n = j & 63;
    mw2t[(size_t)n * 512 + k] = f2bf(mw2[j]);
  } else if (i < 493568) {          // W3 pad: [256,7] -> [256,8]
    int j = i - 491520, d = j >> 3, c = j & 7;
    w3p[j] = (c < 7) ? W3[d * 7 + c] : 0.f;
  }
}

// ---------------- GEMM core: 128x128 tile, BK=64, 4 waves, 2-phase dbuf pipeline ----
#define GEMM_STAGE(buf, k0)                                                        \
  _Pragma("unroll")                                                                \
  for (int r = 0; r < 4; ++r) {                                                    \
    const int row = r * 32 + wid * 8 + srow8;                                      \
    int ga = bm + row; ga = ga < M_ ? ga : M_ - 1;                                 \
    int gb = bn + row; gb = gb < N_ ? gb : N_ - 1;                                 \
    __builtin_amdgcn_global_load_lds((gas_p)(pA_ + ((size_t)ga * lda_ + (k0)) * 2 + sks * 16), \
                                     (las_p)(ldsA[buf] + row * 64), 16, 0, 0);     \
    __builtin_amdgcn_global_load_lds((gas_p)(pB_ + ((size_t)gb * ldb_ + (k0)) * 2 + sks * 16), \
                                     (las_p)(ldsB[buf] + row * 64), 16, 0, 0);     \
  }

#define GEMM_BODY(A, lda, Bt, ldb_K, M, Ncols, K, bm, bn)                          \
  __shared__ unsigned short ldsA[2][128 * 64];                                     \
  __shared__ unsigned short ldsB[2][128 * 64];                                     \
  const char* pA_ = (const char*)(A);                                              \
  const char* pB_ = (const char*)(Bt);                                             \
  const int lda_ = (lda), ldb_ = (ldb_K), M_ = (M), N_ = (Ncols);                  \
  const int tid  = threadIdx.x;                                                    \
  const int lane = tid & 63;                                                       \
  const int wid  = tid >> 6;                                                       \
  const int wm   = (wid >> 1) << 6;                                                \
  const int wn   = (wid & 1) << 6;                                                 \
  f32x4 acc[4][4] = {};                                                            \
  const int srow8 = lane >> 3;                                                     \
  const int sks   = (lane & 7) ^ srow8;                                            \
  const int nt    = (K) >> 6;                                                      \
  GEMM_STAGE(0, 0)                                                                 \
  for (int t = 0; t < nt; ++t) {                                                   \
    const int cur = t & 1;                                                         \
    if (t + 1 < nt) {                                                              \
      GEMM_STAGE(cur ^ 1, (t + 1) << 6)                                            \
      asm volatile("s_waitcnt vmcnt(8)" ::: "memory");                             \
    } else {                                                                       \
      asm volatile("s_waitcnt vmcnt(0)" ::: "memory");                             \
    }                                                                              \
    __builtin_amdgcn_s_barrier();                                                  \
    __builtin_amdgcn_sched_barrier(0);                                             \
    const int q   = lane >> 4;                                                     \
    const int r15 = lane & 15;                                                     \
    _Pragma("unroll")                                                              \
    for (int kk = 0; kk < 2; ++kk) {                                               \
      bf16x8 af[4], bfr[4];                                                        \
      _Pragma("unroll")                                                            \
      for (int m = 0; m < 4; ++m) {                                                \
        const int ra = wm + m * 16 + r15;                                          \
        af[m]  = *(const bf16x8*)(ldsA[cur] + ra * 64 + (((kk << 2) + q) ^ (ra & 7)) * 8); \
        const int rb = wn + m * 16 + r15;                                          \
        bfr[m] = *(const bf16x8*)(ldsB[cur] + rb * 64 + (((kk << 2) + q) ^ (rb & 7)) * 8); \
      }                                                                            \
      _Pragma("unroll")                                                            \
      for (int m = 0; m < 4; ++m)                                                  \
        _Pragma("unroll")                                                          \
        for (int n = 0; n < 4; ++n)                                                \
          acc[m][n] = __builtin_amdgcn_mfma_f32_16x16x32_bf16(af[m], bfr[n], acc[m][n], 0, 0, 0); \
    }                                                                              \
    __builtin_amdgcn_sched_barrier(0);                                             \
    __builtin_amdgcn_s_barrier();                                                  \
  }

// ---------------- generic GEMM ----------------
template<bool RELU, bool BIAS>
__global__ __launch_bounds__(256)
void gemm_bf16(const unsigned short* __restrict__ A, int lda,
               const unsigned short* __restrict__ Bt,
               const float* __restrict__ bias,
               unsigned short* __restrict__ C, int ldc,
               int M, int N, int K)
{
  const int nwg  = gridDim.x * gridDim.y;
  const int wgid = xcd_swizzle(blockIdx.y * gridDim.x + blockIdx.x, nwg);
  const int bn   = (wgid % gridDim.x) << 7;
  const int bm   = (wgid / gridDim.x) << 7;

  GEMM_BODY(A, lda, Bt, K, M, N, K, bm, bn)

  const int q   = lane >> 4;
  const int r15 = lane & 15;
#pragma unroll
  for (int m = 0; m < 4; ++m) {
#pragma unroll
    for (int n = 0; n < 4; ++n) {
      const int gc = bn + wn + n * 16 + r15;
#pragma unroll
      for (int i = 0; i < 4; ++i) {
        const int gr = bm + wm + m * 16 + q * 4 + i;
        if (gr < M && gc < N) {
          float f = acc[m][n][i];
          if (BIAS) f += bias[gc];
          if (RELU) f = fmaxf(f, 0.f);
          C[(size_t)gr * ldc + gc] = f2bf(f);
        }
      }
    }
  }
}

// ---------------- fused MLP1+GCN1 GEMM: A=x_bf [M,512], Bt=[768,512] ----------------
__global__ __launch_bounds__(256)
void gemm_fused(const unsigned short* __restrict__ A,
                const unsigned short* __restrict__ Bt,
                const float* __restrict__ mb1,
                unsigned short* __restrict__ h1,
                unsigned short* __restrict__ g1,
                int M)
{
  const int nwg  = gridDim.x * gridDim.y;
  const int wgid = xcd_swizzle(blockIdx.y * gridDim.x + blockIdx.x, nwg);
  const int bnt  = wgid % gridDim.x;
  const int bn   = bnt << 7;
  const int bm   = (wgid / gridDim.x) << 7;

  GEMM_BODY(A, 512, Bt, 512, M, 768, 512, bm, bn)

  const int q   = lane >> 4;
  const int r15 = lane & 15;
  if (bnt < 4) {   // h1: bias + relu
#pragma unroll
    for (int m = 0; m < 4; ++m) {
#pragma unroll
      for (int n = 0; n < 4; ++n) {
        const int gc = bn + wn + n * 16 + r15;
        const float b = mb1[gc];
#pragma unroll
        for (int i = 0; i < 4; ++i) {
          const int gr = bm + wm + m * 16 + q * 4 + i;
          if (gr < M) h1[(size_t)gr * 512 + gc] = f2bf(fmaxf(acc[m][n][i] + b, 0.f));
        }
      }
    }
  } else {         // g1: plain
#pragma unroll
    for (int m = 0; m < 4; ++m) {
#pragma unroll
      for (int n = 0; n < 4; ++n) {
        const int gc = bn - 512 + wn + n * 16 + r15;
#pragma unroll
        for (int i = 0; i < 4; ++i) {
          const int gr = bm + wm + m * 16 + q * 4 + i;
          if (gr < M) g1[(size_t)gr * 256 + gc] = f2bf(acc[m][n][i]);
        }
      }
    }
  }
}

// ---------------- logits ----------------
__global__ __launch_bounds__(256)
void logits_kernel(const unsigned short* __restrict__ h2, const float* __restrict__ mw3,
                   const float* __restrict__ mb3, const float* __restrict__ par,
                   float* __restrict__ Lg, float* __restrict__ Tg)
{
  __shared__ float w[64 * 8];
  __shared__ float P[64];
  int tid = threadIdx.x;
  for (int i = tid; i < 512; i += 256) {
    int k = i >> 3, c = i & 7;
    w[i] = (c < 7) ? mw3[k * 7 + c] : 0.f;
  }
  if (tid < 64) {
    int d = tid >> 3, c = tid & 7;
    P[tid] = (d < 7 && c < 7) ? fmaxf(2.0f * par[d * 7 + c], 0.f) : 0.f;
  }
  __syncthreads();
  int n = blockIdx.x * 256 + tid;
  if (n >= NN) return;
  const unsigned short* hr = h2 + (size_t)n * 64;
  f32x4 L0 = {0,0,0,0}, L1 = {0,0,0,0};
  for (int k = 0; k < 64; k += 4) {
    ushort4 v = *(const ushort4*)(hr + k);
    float xs[4] = {bf2f(v.x), bf2f(v.y), bf2f(v.z), bf2f(v.w)};
#pragma unroll
    for (int j = 0; j < 4; ++j) {
      L0 += xs[j] * *(const f32x4*)&w[(k + j) * 8];
      L1 += xs[j] * *(const f32x4*)&w[(k + j) * 8 + 4];
    }
  }
  float Ls[8] = {L0[0], L0[1], L0[2], L0[3], L1[0], L1[1], L1[2], 0.f};
#pragma unroll
  for (int c = 0; c < 7; ++c) Ls[c] += mb3[c];
  f32x4 T0 = {0,0,0,0}, T1 = {0,0,0,0};
#pragma unroll
  for (int d = 0; d < 7; ++d) {
    T0 += Ls[d] * *(const f32x4*)&P[d * 8];
    T1 += Ls[d] * *(const f32x4*)&P[d * 8 + 4];
  }
  f32x4 o0 = {Ls[0], Ls[1], Ls[2], Ls[3]};
  f32x4 o1 = {Ls[4], Ls[5], Ls[6], 0.f};
  *(f32x4*)(Lg + (size_t)n * 8)     = o0;
  *(f32x4*)(Lg + (size_t)n * 8 + 4) = o1;
  *(f32x4*)(Tg + (size_t)n * 8)     = T0;
  *(f32x4*)(Tg + (size_t)n * 8 + 4) = T1;
}

// ---------------- edge pass 1: 2 edges/thread; ew + cnt atomic (rank captured) ----
__global__ __launch_bounds__(256)
void edge1_kernel(const int* __restrict__ row, const int* __restrict__ col,
                  const float* __restrict__ Lg, const float* __restrict__ Tg,
                  float* __restrict__ ew_raw, int* __restrict__ cnt,
                  unsigned short* __restrict__ rk, double* __restrict__ part)
{
  __shared__ double shs[4], shs2[4];
  const int e0 = blockIdx.x * 512 + threadIdx.x;
  const int e1 = e0 + 256;
  double s = 0.0, s2 = 0.0;
  if (e1 < EE) {
    int r0 = row[e0], c0 = col[e0];
    int r1 = row[e1], c1 = col[e1];
    float4 a00 = *(const float4*)(Lg + (size_t)r0 * 8);
    float4 a01 = *(const float4*)(Lg + (size_t)r0 * 8 + 4);
    float4 a10 = *(const float4*)(Lg + (size_t)r1 * 8);
    float4 a11 = *(const float4*)(Lg + (size_t)r1 * 8 + 4);
    float4 b00 = *(const float4*)(Tg + (size_t)c0 * 8);
    float4 b01 = *(const float4*)(Tg + (size_t)c0 * 8 + 4);
    float4 b10 = *(const float4*)(Tg + (size_t)c1 * 8);
    float4 b11 = *(const float4*)(Tg + (size_t)c1 * 8 + 4);
    float v0 = a00.x*b00.x + a00.y*b00.y + a00.z*b00.z + a00.w*b00.w
             + a01.x*b01.x + a01.y*b01.y + a01.z*b01.z + a01.w*b01.w;
    float v1 = a10.x*b10.x + a10.y*b10.y + a10.z*b10.z + a10.w*b10.w
             + a11.x*b11.x + a11.y*b11.y + a11.z*b11.z + a11.w*b11.w;
    ew_raw[e0] = v0; ew_raw[e1] = v1;
    int p0 = atomicAdd(&cnt[c0], 1);
    int p1 = atomicAdd(&cnt[c1], 1);
    rk[e0] = (unsigned short)p0;
    rk[e1] = (unsigned short)p1;
    s = (double)v0 + (double)v1;
    s2 = (double)v0 * (double)v0 + (double)v1 * (double)v1;
  } else if (e0 < EE) {
    int r0 = row[e0], c0 = col[e0];
    float4 a00 = *(const float4*)(Lg + (size_t)r0 * 8);
    float4 a01 = *(const float4*)(Lg + (size_t)r0 * 8 + 4);
    float4 b00 = *(const float4*)(Tg + (size_t)c0 * 8);
    float4 b01 = *(const float4*)(Tg + (size_t)c0 * 8 + 4);
    float v0 = a00.x*b00.x + a00.y*b00.y + a00.z*b00.z + a00.w*b00.w
             + a01.x*b01.x + a01.y*b01.y + a01.z*b01.z + a01.w*b01.w;
    ew_raw[e0] = v0;
    int p0 = atomicAdd(&cnt[c0], 1);
    rk[e0] = (unsigned short)p0;
    s = (double)v0; s2 = (double)v0 * (double)v0;
  }
  for (int off = 32; off; off >>= 1) {
    s  += __shfl_down(s, off);
    s2 += __shfl_down(s2, off);
  }
  int wv = threadIdx.x >> 6;
  if ((threadIdx.x & 63) == 0) { shs[wv] = s; shs2[wv] = s2; }
  __syncthreads();
  if (threadIdx.x == 0) {
    part[blockIdx.x]         = shs[0] + shs[1] + shs[2] + shs[3];
    part[NB_E1 + blockIdx.x] = shs2[0] + shs2[1] + shs2[2] + shs2[3];
  }
}

// ---------------- reduce edge1 partials -> red ----------------
__global__ __launch_bounds__(1024)
void redpart_kernel(const double* __restrict__ part, double* __restrict__ red)
{
  __shared__ double sh[16][2];
  int tid = threadIdx.x;
  double s = 0.0, s2 = 0.0;
  for (int i = tid; i < NB_E1; i += 1024) {
    s  += part[i];
    s2 += part[NB_E1 + i];
  }
  for (int off = 32; off; off >>= 1) {
    s  += __shfl_down(s, off);
    s2 += __shfl_down(s2, off);
  }
  if ((tid & 63) == 0) { sh[tid >> 6][0] = s; sh[tid >> 6][1] = s2; }
  __syncthreads();
  if (tid == 0) {
    double a = 0.0, b = 0.0;
    for (int i = 0; i < 16; ++i) { a += sh[i][0]; b += sh[i][1]; }
    red[0] = a; red[1] = b;
  }
}

// ---------------- edge pass 2: standardize + CSR place at rowptr[c]+rk[e] (NO atomics) ----
__global__ __launch_bounds__(256)
void edge2_kernel(const int* __restrict__ row, const int* __restrict__ col,
                  const float* __restrict__ ew_raw, const unsigned short* __restrict__ rk,
                  const double* __restrict__ red, const int* __restrict__ rowptr,
                  int2* __restrict__ csr_sw)
{
  int e = blockIdx.x * 256 + threadIdx.x;
  if (e >= EE) return;
  double mean = red[0] / (double)EE;
  double var  = (red[1] - (double)EE * mean * mean) / (double)(EE - 1);
  double scl  = sqrt(1e-4 / var);
  float v = (float)(((double)ew_raw[e] - mean) * scl) + 1.0f;
  int r = row[e], c = col[e];
  int2 sw; sw.x = r; sw.y = __float_as_int(v);
  csr_sw[rowptr[c] + (int)rk[e]] = sw;
}

// ---------------- deg from CSR rows (no atomics) + dinv ----------------
__global__ __launch_bounds__(256)
void degdinv_kernel(const int* __restrict__ rowptr, const int2* __restrict__ csr_sw,
                    float* __restrict__ dinv)
{
  int n = blockIdx.x * 256 + threadIdx.x;
  if (n >= NN) return;
  int s = rowptr[n], e = rowptr[n + 1];
  float deg = 0.f;
  for (int i = s; i < e; ++i) deg += __int_as_float(csr_sw[i].y);
  float d = deg + 1.0f;   // + self-loop weight 1
  dinv[n] = d > 0.f ? 1.0f / sqrtf(fmaxf(d, 1e-12f)) : 0.f;
}

// ---------------- scale csr weights by dinv[src] (coalesced) ----------------
__global__ __launch_bounds__(256)
void scale_csr_kernel(int2* __restrict__ csr_sw, const float* __restrict__ dinv)
{
  int i = blockIdx.x * 256 + threadIdx.x;
  if (i >= EE) return;
  int2 sw = csr_sw[i];
  sw.y = __float_as_int(__int_as_float(sw.y) * dinv[sw.x]);
  csr_sw[i] = sw;
}

// ---------------- parallel 3-stage exclusive scan of cnt -> rowptr ----------------
__global__ __launch_bounds__(256)
void scan1_kernel(const int* __restrict__ cnt, int* __restrict__ bsum)
{
  __shared__ int sh[4];
  int i = blockIdx.x * 256 + threadIdx.x;
  int v = (i < NN) ? cnt[i] : 0;
  for (int off = 32; off; off >>= 1) v += __shfl_down(v, off);
  if ((threadIdx.x & 63) == 0) sh[threadIdx.x >> 6] = v;
  __syncthreads();
  if (threadIdx.x == 0) bsum[blockIdx.x] = sh[0] + sh[1] + sh[2] + sh[3];
}

__global__ __launch_bounds__(256)
void scan2_kernel(int* __restrict__ bsum)
{
  __shared__ int sh[256];
  int tid = threadIdx.x;
  int v = (tid < NB_SCAN) ? bsum[tid] : 0;
  sh[tid] = v;
  __syncthreads();
  for (int off = 1; off < 256; off <<= 1) {
    int t = (tid >= off) ? sh[tid - off] : 0;
    __syncthreads();
    sh[tid] += t;
    __syncthreads();
  }
  if (tid < NB_SCAN) bsum[tid] = sh[tid] - v;   // exclusive
}

__global__ __launch_bounds__(256)
void scan3_kernel(const int* __restrict__ cnt, const int* __restrict__ bsum,
                  int* __restrict__ rowptr)
{
  __shared__ int sh[256];
  int tid = threadIdx.x;
  int i = blockIdx.x * 256 + tid;
  int v = (i < NN) ? cnt[i] : 0;
  sh[tid] = v;
  __syncthreads();
  for (int off = 1; off < 256; off <<= 1) {
    int t = (tid >= off) ? sh[tid - off] : 0;
    __syncthreads();
    sh[tid] += t;
    __syncthreads();
  }
  if (i < NN) rowptr[i + 1] = bsum[blockIdx.x] + sh[tid];
  if (i == 0) rowptr[0] = 0;
}

// ---------------- dim-256 aggregation: one node per HALF-WAVE, persistent grid ----
// grid = 1536; natural VGPR (launch_bounds(256,6) caused spills -- R11)
#define AGG_ACC(sw_, v_)                                                     \
  {                                                                          \
    float w_ = __int_as_float((sw_).y);                                      \
    a0 += w_ * bf2f((v_)[0]); a1 += w_ * bf2f((v_)[1]);                      \
    a2 += w_ * bf2f((v_)[2]); a3 += w_ * bf2f((v_)[3]);                      \
    a4 += w_ * bf2f((v_)[4]); a5 += w_ * bf2f((v_)[5]);                      \
    a6 += w_ * bf2f((v_)[6]); a7 += w_ * bf2f((v_)[7]);                      \
  }

template<int MODE>
__global__ __launch_bounds__(256)
void agg256_kernel(const int* __restrict__ rowptr, const int2* __restrict__ csr_sw,
                   const unsigned short* __restrict__ gsrc,
                   const float* __restrict__ dinv, const float* __restrict__ bias,
                   const unsigned short* __restrict__ h0in,
                   unsigned short* __restrict__ h0out,
                   unsigned short* __restrict__ xout,
                   const float* __restrict__ w3p, float* __restrict__ y3)
{
  const int tid = threadIdx.x;
  const int hw  = tid >> 5;          // half-wave 0..7
  const int l5  = tid & 31;
  const size_t colbase = (size_t)(l5 << 3);
  const int stride = (int)gridDim.x * 8;

  for (int n = blockIdx.x * 8 + hw; n < NN; n += stride) {
    const int dbase = l5 << 3;
    // hoist independent loads: self-loop row, bias, dinv
    const float dn = dinv[n];
    u16x8 sv = *(const u16x8*)(gsrc + (size_t)n * 256 + dbase);
    float4 b0 = *(const float4*)(bias + dbase);
    float4 b1 = *(const float4*)(bias + dbase + 4);
    float a0=0,a1=0,a2=0,a3=0,a4=0,a5=0,a6=0,a7=0;
    const int s = rowptr[n], e = rowptr[n + 1];
    int i = s;
    for (; i + 7 < e; i += 8) {               // 8 gathers in flight
      int2 sw[8];
#pragma unroll
      for (int u = 0; u < 8; ++u) sw[u] = csr_sw[i + u];
      u16x8 v[8];
#pragma unroll
      for (int u = 0; u < 8; ++u) v[u] = *(const u16x8*)(gsrc + (size_t)sw[u].x * 256 + colbase);
#pragma unroll
      for (int u = 0; u < 8; ++u) AGG_ACC(sw[u], v[u])
    }
    for (; i + 3 < e; i += 4) {
      int2 sw[4];
#pragma unroll
      for (int u = 0; u < 4; ++u) sw[u] = csr_sw[i + u];
      u16x8 v[4];
#pragma unroll
      for (int u = 0; u < 4; ++u) v[u] = *(const u16x8*)(gsrc + (size_t)sw[u].x * 256 + colbase);
#pragma unroll
      for (int u = 0; u < 4; ++u) AGG_ACC(sw[u], v[u])
    }
    for (; i < e; ++i) {
      int2 sw = csr_sw[i];
      u16x8 v = *(const u16x8*)(gsrc + (size_t)sw.x * 256 + colbase);
      AGG_ACC(sw, v)
    }
    const float wd = dn * dn;
    float f0 = dn * a0 + wd * bf2f(sv[0]) + b0.x;
    float f1 = dn * a1 + wd * bf2f(sv[1]) + b0.y;
    float f2 = dn * a2 + wd * bf2f(sv[2]) + b0.z;
    float f3 = dn * a3 + wd * bf2f(sv[3]) + b0.w;
    float f4 = dn * a4 + wd * bf2f(sv[4]) + b1.x;
    float f5 = dn * a5 + wd * bf2f(sv[5]) + b1.y;
    float f6 = dn * a6 + wd * bf2f(sv[6]) + b1.z;
    float f7 = dn * a7 + wd * bf2f(sv[7]) + b1.w;
    const size_t o = (size_t)n * 256 + dbase;
    if (MODE == 0) {
      u16x8 h;
      h[0] = f2bf(f0); h[1] = f2bf(f1); h[2] = f2bf(f2); h[3] = f2bf(f3);
      h[4] = f2bf(f4); h[5] = f2bf(f5); h[6] = f2bf(f6); h[7] = f2bf(f7);
      *(u16x8*)(h0out + o) = h;
      u16x8 xo;
      xo[0] = f2bf(fmaxf(f0, 0.f)); xo[1] = f2bf(fmaxf(f1, 0.f));
      xo[2] = f2bf(fmaxf(f2, 0.f)); xo[3] = f2bf(fmaxf(f3, 0.f));
      xo[4] = f2bf(fmaxf(f4, 0.f)); xo[5] = f2bf(fmaxf(f5, 0.f));
      xo[6] = f2bf(fmaxf(f6, 0.f)); xo[7] = f2bf(fmaxf(f7, 0.f));
      *(u16x8*)(xout + o) = xo;
    } else {
      u16x8 h = *(const u16x8*)(h0in + o);
      float xv0 = bf2f(f2bf(fmaxf(f0, 0.f) + bf2f(h[0])));
      float xv1 = bf2f(f2bf(fmaxf(f1, 0.f) + bf2f(h[1])));
      float xv2 = bf2f(f2bf(fmaxf(f2, 0.f) + bf2f(h[2])));
      float xv3 = bf2f(f2bf(fmaxf(f3, 0.f) + bf2f(h[3])));
      float xv4 = bf2f(f2bf(fmaxf(f4, 0.f) + bf2f(h[4])));
      float xv5 = bf2f(f2bf(fmaxf(f5, 0.f) + bf2f(h[5])));
      float xv6 = bf2f(f2bf(fmaxf(f6, 0.f) + bf2f(h[6])));
      float xv7 = bf2f(f2bf(fmaxf(f7, 0.f) + bf2f(h[7])));
      const float* w3r = w3p + (size_t)dbase * 8;
      f32x4 p0 = {0,0,0,0}, p1 = {0,0,0,0};
      p0 += xv0 * *(const f32x4*)(w3r +  0); p1 += xv0 * *(const f32x4*)(w3r +  4);
      p0 += xv1 * *(const f32x4*)(w3r +  8); p1 += xv1 * *(const f32x4*)(w3r + 12);
      p0 += xv2 * *(const f32x4*)(w3r + 16); p1 += xv2 * *(const f32x4*)(w3r + 20);
      p0 += xv3 * *(const f32x4*)(w3r + 24); p1 += xv3 * *(const f32x4*)(w3r + 28);
      p0 += xv4 * *(const f32x4*)(w3r + 32); p1 += xv4 * *(const f32x4*)(w3r + 36);
      p0 += xv5 * *(const f32x4*)(w3r + 40); p1 += xv5 * *(const f32x4*)(w3r + 44);
      p0 += xv6 * *(const f32x4*)(w3r + 48); p1 += xv6 * *(const f32x4*)(w3r + 52);
      p0 += xv7 * *(const f32x4*)(w3r + 56); p1 += xv7 * *(const f32x4*)(w3r + 60);
#pragma unroll
      for (int off = 1; off < 32; off <<= 1) {
        p0[0] += __shfl_xor(p0[0], off); p0[1] += __shfl_xor(p0[1], off);
        p0[2] += __shfl_xor(p0[2], off); p0[3] += __shfl_xor(p0[3], off);
        p1[0] += __shfl_xor(p1[0], off); p1[1] += __shfl_xor(p1[1], off);
        p1[2] += __shfl_xor(p1[2], off); p1[3] += __shfl_xor(p1[3], off);
      }
      if (l5 == 0) {
        *(f32x4*)(y3 + (size_t)n * 8)     = p0;
        *(f32x4*)(y3 + (size_t)n * 8 + 4) = p1;
      }
    }
  }
}

// ---------------- dim-7 aggregation: 8 lanes per node, 4-deep ILP ----------------
__global__ __launch_bounds__(256)
void agg7_kernel(const int* __restrict__ rowptr, const int2* __restrict__ csr_sw,
                 const float* __restrict__ y3,
                 const float* __restrict__ dinv, const float* __restrict__ b3,
                 float* __restrict__ out)
{
  int n = blockIdx.x * 32 + (threadIdx.x >> 3);
  if (n >= NN) return;
  int j = threadIdx.x & 7;
  float acc = 0.f;
  int s = rowptr[n], e = rowptr[n + 1];
  int i = s;
  for (; i + 3 < e; i += 4) {
    int2 sw0 = csr_sw[i],     sw1 = csr_sw[i + 1];
    int2 sw2 = csr_sw[i + 2], sw3 = csr_sw[i + 3];
    float v0 = y3[(size_t)sw0.x * 8 + j];
    float v1 = y3[(size_t)sw1.x * 8 + j];
    float v2 = y3[(size_t)sw2.x * 8 + j];
    float v3 = y3[(size_t)sw3.x * 8 + j];
    acc += __int_as_float(sw0.y) * v0 + __int_as_float(sw1.y) * v1
         + __int_as_float(sw2.y) * v2 + __int_as_float(sw3.y) * v3;
  }
  for (; i < e; ++i) {
    int2 sw = csr_sw[i];
    acc += __int_as_float(sw.y) * y3[(size_t)sw.x * 8 + j];
  }
  float dn = dinv[n];
  acc = dn * acc + dn * dn * y3[(size_t)n * 8 + j];
  if (j < 7) out[(size_t)n * 7 + j] = acc + b3[j];
}

// ---------------- host ----------------
extern "C" void kernel_launch(void* const* d_in, const int* in_sizes, int n_in,
                              void* d_out, int out_size, void* d_ws, size_t ws_size,
                              hipStream_t stream)
{
  const float* x   = (const float*)d_in[0];
  const int*   ei  = (const int*)d_in[1];
  const float* W1  = (const float*)d_in[2];
  const float* b1  = (const float*)d_in[3];
  const float* W2  = (const float*)d_in[4];
  const float* b2  = (const float*)d_in[5];
  const float* W3  = (const float*)d_in[6];
  const float* b3  = (const float*)d_in[7];
  const float* mw1 = (const float*)d_in[8];
  const float* mb1 = (const float*)d_in[9];
  const float* mw2 = (const float*)d_in[10];
  const float* mb2 = (const float*)d_in[11];
  const float* mw3 = (const float*)d_in[12];
  const float* mb3 = (const float*)d_in[13];
  const float* par = (const float*)d_in[14];
  const int* row = ei;
  const int* col = ei + EE;
  float* out = (float*)d_out;

  char* ws = (char*)d_ws;
  unsigned short* x_bf  = (unsigned short*)(ws + O_XBF);
  unsigned short* h0    = (unsigned short*)(ws + O_XBF);   // bf16, alias (x_bf dead after fused GEMM)
  unsigned short* h1_bf = (unsigned short*)(ws + O_H1);
  unsigned short* g2_bf = (unsigned short*)(ws + O_H1);    // reuse (h1 dead)
  unsigned short* g1_bf = (unsigned short*)(ws + O_G1);
  unsigned short* x1_bf = (unsigned short*)(ws + O_X1);
  unsigned short* h2_bf = (unsigned short*)(ws + O_H2);
  float* Lg      = (float*)(ws + O_LG);
  float* Tg      = (float*)(ws + O_TG);
  float* ew_raw  = (float*)(ws + O_EWR);
  float* y3      = (float*)(ws + O_EWR);                   // reuse (ew_raw dead after edge2)
  float* w3p     = (float*)(ws + O_W3P);
  unsigned short* rk = (unsigned short*)(ws + O_RK);
  int2*  csr_sw  = (int2*)(ws + O_CSR);
  double* part   = (double*)(ws + O_CSR);                  // alias: consumed before edge2 fills csr
  unsigned short* mw1t = (unsigned short*)(ws + O_MW1T);   // fused Bt = [mw1t; w1t], 768 rows
  unsigned short* w1t  = (unsigned short*)(ws + O_W1T);
  unsigned short* w2t  = (unsigned short*)(ws + O_W2T);
  unsigned short* mw2t = (unsigned short*)(ws + O_MW2T);
  int*    cnt    = (int*)(ws + O_CNT);
  double* red    = (double*)(ws + O_RED);
  int*    rowptr = (int*)(ws + O_RPT);
  float*  dinv   = (float*)(ws + O_DINV);
  int*    bsum   = (int*)(ws + O_BSUM);

  // zero: cnt
  hipMemsetAsync(ws + O_CNT, 0, 200192, stream);

  // fp32 -> bf16 conversions (+ padded W3)
  conv_f2bf4<<<25000, 256, 0, stream>>>(x, x_bf, NN * 512 / 4);
  conv_weights<<<1929, 256, 0, stream>>>(mw1, W1, W2, mw2, W3, mw1t, w1t, w2t, mw2t, w3p);

  // fused MLP1 + GCN1 GEMM
  gemm_fused<<<dim3(6, 391), 256, 0, stream>>>(x_bf, mw1t, mb1, h1_bf, g1_bf, NN);
  // MLP layer 2
  gemm_bf16<true,  true ><<<dim3(1, 391), 256, 0, stream>>>(h1_bf, 512, mw2t, mb2, h2_bf, 64, NN, 64, 512);
  logits_kernel<<<196, 256, 0, stream>>>(h2_bf, mw3, mb3, par, Lg, Tg);

  // edge weights + CSR (rank captured in edge1's cnt atomic; edge2 is atomic-free)
  edge1_kernel<<<NB_E1, 256, 0, stream>>>(row, col, Lg, Tg, ew_raw, cnt, rk, part);
  redpart_kernel<<<1, 1024, 0, stream>>>(part, red);
  scan1_kernel<<<NB_SCAN, 256, 0, stream>>>(cnt, bsum);
  scan2_kernel<<<1, 256, 0, stream>>>(bsum);
  scan3_kernel<<<NB_SCAN, 256, 0, stream>>>(cnt, bsum, rowptr);
  edge2_kernel<<<NB_EDGE, 256, 0, stream>>>(row, col, ew_raw, rk, red, rowptr, csr_sw);
  degdinv_kernel<<<196, 256, 0, stream>>>(rowptr, csr_sw, dinv);
  scale_csr_kernel<<<NB_EDGE, 256, 0, stream>>>(csr_sw, dinv);

  // GCN layer 0 aggregation (persistent grid)
  agg256_kernel<0><<<1536, 256, 0, stream>>>(rowptr, csr_sw, g1_bf, dinv, b1, nullptr, h0, x1_bf, nullptr, nullptr);
  // GCN layer 1 (+residual h0), fused with W3 gemv -> y3
  gemm_bf16<false, false><<<dim3(2, 391), 256, 0, stream>>>(x1_bf, 256, w2t, nullptr, g2_bf, 256, NN, 256, 256);
  agg256_kernel<1><<<1536, 256, 0, stream>>>(rowptr, csr_sw, g2_bf, dinv, b2, h0, nullptr, nullptr, w3p, y3);
  // final dim-7 aggregation
  agg7_kernel<<<1563, 256, 0, stream>>>(rowptr, csr_sw, y3, dinv, b3, out);
}

// Round 15
// 371.892 us; speedup vs baseline: 1.3618x; 1.0142x over previous
//
#include <hip/hip_runtime.h>

#define NN 50000
#define EE 800000
#define NB_EDGE 3125   // ceil(EE/256)
#define NB_E1   782    // ceil(EE/1024) for 4-edge-per-thread edge1
#define NB_SCAN 196    // ceil(NN/256)

typedef __attribute__((ext_vector_type(4))) float f32x4;
typedef __attribute__((ext_vector_type(8))) short bf16x8;
typedef __attribute__((ext_vector_type(8))) unsigned short u16x8;

typedef const __attribute__((address_space(1))) void* gas_p;
typedef __attribute__((address_space(3))) void* las_p;

__device__ __forceinline__ float bf2f(unsigned short u) {
  union { unsigned int i; float f; } v; v.i = ((unsigned int)u) << 16; return v.f;
}
__device__ __forceinline__ unsigned short f2bf(float f) {
  union { float f; unsigned int i; } v; v.f = f;
  unsigned int u = v.i;
  return (unsigned short)((u + 0x7FFFu + ((u >> 16) & 1u)) >> 16);
}

// bijective XCD swizzle (m204)
__device__ __forceinline__ int xcd_swizzle(int orig, int nwg) {
  int xcd = orig & 7;
  int pos = orig >> 3;
  int q = nwg >> 3, r = nwg & 7;
  return (xcd < r ? xcd * (q + 1) : r * (q + 1) + (xcd - r) * q) + pos;
}

// ---------------- workspace layout (bytes, all 256-aligned) ----------------
constexpr size_t O_XBF  = 0;                  // x_bf [50000,512]bf16; reused as h0 [50000,256]bf16
constexpr size_t O_H1   = O_XBF + 51200000;   // h1 [50000,512]bf16; reused as g2
constexpr size_t O_G1   = O_H1  + 51200000;   // g1 [50000,256]bf16
constexpr size_t O_X1   = O_G1  + 25600000;   // x1 [50000,256]bf16
constexpr size_t O_H2   = O_X1  + 25600000;   // (unused now)
constexpr size_t O_LG   = O_H2  + 6400000;    // Lg [50000,8]f32
constexpr size_t O_TG   = O_LG  + 1600000;    // Tg [50000,8]f32
constexpr size_t O_EWR  = O_TG  + 1600000;    // ew_raw [E]f32; reused as y3 [50000,8]f32
constexpr size_t O_W3P  = O_EWR + 3200000;    // w3p [256][8]f32 (8KB)
constexpr size_t O_RK   = O_W3P + 8192;       // rk [E]u16 (1.6MB)
constexpr size_t O_MW3P = O_RK  + 1600000;    // mw3p [64][8]f32 (2KB)
constexpr size_t O_CSR  = O_W3P + 3200000;    // csr_sw [E]int2 (aliased: edge1 partials, consumed first)
constexpr size_t O_MW1T = O_CSR + 6400000;    // 512*512 bf16   <- fused Bt starts here
constexpr size_t O_W1T  = O_MW1T + 524288;    // 256*512 bf16   (contiguous: 768 rows total)
constexpr size_t O_W2T  = O_W1T  + 262144;    // 256*256 bf16
constexpr size_t O_MW2T = O_W2T  + 131072;    // 64*512 bf16
constexpr size_t O_CNT  = O_MW2T + 65536;     // [N]i32   <- zeroed
constexpr size_t O_RED  = O_CNT  + 200192;    // 2 doubles
constexpr size_t O_RPT  = O_RED  + 256;       // [N+1]i32
constexpr size_t O_DINV = O_RPT  + 200192;    // [N]f32
constexpr size_t O_BSUM = O_DINV + 200192;    // [NB_SCAN]i32

// ---------------- conversions ----------------
__global__ __launch_bounds__(256) void conv_f2bf4(const float* __restrict__ in,
                                                  unsigned short* __restrict__ out, int n4) {
  int i = blockIdx.x * 256 + threadIdx.x;
  if (i >= n4) return;
  const float4 v = ((const float4*)in)[i];
  ushort4 o; o.x = f2bf(v.x); o.y = f2bf(v.y); o.z = f2bf(v.z); o.w = f2bf(v.w);
  ((ushort4*)out)[i] = o;
}

__global__ __launch_bounds__(256)
void conv_weights(const float* __restrict__ mw1, const float* __restrict__ W1,
                  const float* __restrict__ W2, const float* __restrict__ mw2,
                  const float* __restrict__ W3, const float* __restrict__ mw3,
                  unsigned short* __restrict__ mw1t, unsigned short* __restrict__ w1t,
                  unsigned short* __restrict__ w2t, unsigned short* __restrict__ mw2t,
                  float* __restrict__ w3p, float* __restrict__ mw3p)
{
  int i = blockIdx.x * 256 + threadIdx.x;
  if (i < 262144) {                 // mw1: [512,512]
    int k = i >> 9, n = i & 511;
    mw1t[(size_t)n * 512 + k] = f2bf(mw1[i]);
  } else if (i < 393216) {          // W1: [512,256]
    int j = i - 262144, k = j >> 8, n = j & 255;
    w1t[(size_t)n * 512 + k] = f2bf(W1[j]);
  } else if (i < 458752) {          // W2: [256,256]
    int j = i - 393216, k = j >> 8, n = j & 255;
    w2t[(size_t)n * 256 + k] = f2bf(W2[j]);
  } else if (i < 491520) {          // mw2: [512,64]
    int j = i - 458752, k = j >> 6, n = j & 63;
    mw2t[(size_t)n * 512 + k] = f2bf(mw2[j]);
  } else if (i < 493568) {          // W3 pad: [256,7] -> [256,8]
    int j = i - 491520, d = j >> 3, c = j & 7;
    w3p[j] = (c < 7) ? W3[d * 7 + c] : 0.f;
  } else if (i < 494080) {          // mw3 pad: [64,7] -> [64,8]
    int j = i - 493568, d = j >> 3, c = j & 7;
    mw3p[j] = (c < 7) ? mw3[d * 7 + c] : 0.f;
  }
}

// ---------------- GEMM core: 128x128 tile, BK=64, 4 waves, 2-phase dbuf pipeline ----
#define GEMM_STAGE(buf, k0)                                                        \
  _Pragma("unroll")                                                                \
  for (int r = 0; r < 4; ++r) {                                                    \
    const int row = r * 32 + wid * 8 + srow8;                                      \
    int ga = bm + row; ga = ga < M_ ? ga : M_ - 1;                                 \
    int gb = bn + row; gb = gb < N_ ? gb : N_ - 1;                                 \
    __builtin_amdgcn_global_load_lds((gas_p)(pA_ + ((size_t)ga * lda_ + (k0)) * 2 + sks * 16), \
                                     (las_p)(ldsA[buf] + row * 64), 16, 0, 0);     \
    __builtin_amdgcn_global_load_lds((gas_p)(pB_ + ((size_t)gb * ldb_ + (k0)) * 2 + sks * 16), \
                                     (las_p)(ldsB[buf] + row * 64), 16, 0, 0);     \
  }

#define GEMM_BODY(A, lda, Bt, ldb_K, M, Ncols, K, bm, bn)                          \
  __shared__ unsigned short ldsA[2][128 * 64];                                     \
  __shared__ unsigned short ldsB[2][128 * 64];                                     \
  const char* pA_ = (const char*)(A);                                              \
  const char* pB_ = (const char*)(Bt);                                             \
  const int lda_ = (lda), ldb_ = (ldb_K), M_ = (M), N_ = (Ncols);                  \
  const int tid  = threadIdx.x;                                                    \
  const int lane = tid & 63;                                                       \
  const int wid  = tid >> 6;                                                       \
  const int wm   = (wid >> 1) << 6;                                                \
  const int wn   = (wid & 1) << 6;                                                 \
  f32x4 acc[4][4] = {};                                                            \
  const int srow8 = lane >> 3;                                                     \
  const int sks   = (lane & 7) ^ srow8;                                            \
  const int nt    = (K) >> 6;                                                      \
  GEMM_STAGE(0, 0)                                                                 \
  for (int t = 0; t < nt; ++t) {                                                   \
    const int cur = t & 1;                                                         \
    if (t + 1 < nt) {                                                              \
      GEMM_STAGE(cur ^ 1, (t + 1) << 6)                                            \
      asm volatile("s_waitcnt vmcnt(8)" ::: "memory");                             \
    } else {                                                                       \
      asm volatile("s_waitcnt vmcnt(0)" ::: "memory");                             \
    }                                                                              \
    __builtin_amdgcn_s_barrier();                                                  \
    __builtin_amdgcn_sched_barrier(0);                                             \
    const int q   = lane >> 4;                                                     \
    const int r15 = lane & 15;                                                     \
    _Pragma("unroll")                                                              \
    for (int kk = 0; kk < 2; ++kk) {                                               \
      bf16x8 af[4], bfr[4];                                                        \
      _Pragma("unroll")                                                            \
      for (int m = 0; m < 4; ++m) {                                                \
        const int ra = wm + m * 16 + r15;                                          \
        af[m]  = *(const bf16x8*)(ldsA[cur] + ra * 64 + (((kk << 2) + q) ^ (ra & 7)) * 8); \
        const int rb = wn + m * 16 + r15;                                          \
        bfr[m] = *(const bf16x8*)(ldsB[cur] + rb * 64 + (((kk << 2) + q) ^ (rb & 7)) * 8); \
      }                                                                            \
      _Pragma("unroll")                                                            \
      for (int m = 0; m < 4; ++m)                                                  \
        _Pragma("unroll")                                                          \
        for (int n = 0; n < 4; ++n)                                                \
          acc[m][n] = __builtin_amdgcn_mfma_f32_16x16x32_bf16(af[m], bfr[n], acc[m][n], 0, 0, 0); \
    }                                                                              \
    __builtin_amdgcn_sched_barrier(0);                                             \
    __builtin_amdgcn_s_barrier();                                                  \
  }

// ---------------- generic GEMM ----------------
template<bool RELU, bool BIAS>
__global__ __launch_bounds__(256)
void gemm_bf16(const unsigned short* __restrict__ A, int lda,
               const unsigned short* __restrict__ Bt,
               const float* __restrict__ bias,
               unsigned short* __restrict__ C, int ldc,
               int M, int N, int K)
{
  const int nwg  = gridDim.x * gridDim.y;
  const int wgid = xcd_swizzle(blockIdx.y * gridDim.x + blockIdx.x, nwg);
  const int bn   = (wgid % gridDim.x) << 7;
  const int bm   = (wgid / gridDim.x) << 7;

  GEMM_BODY(A, lda, Bt, K, M, N, K, bm, bn)

  const int q   = lane >> 4;
  const int r15 = lane & 15;
#pragma unroll
  for (int m = 0; m < 4; ++m) {
#pragma unroll
    for (int n = 0; n < 4; ++n) {
      const int gc = bn + wn + n * 16 + r15;
#pragma unroll
      for (int i = 0; i < 4; ++i) {
        const int gr = bm + wm + m * 16 + q * 4 + i;
        if (gr < M && gc < N) {
          float f = acc[m][n][i];
          if (BIAS) f += bias[gc];
          if (RELU) f = fmaxf(f, 0.f);
          C[(size_t)gr * ldc + gc] = f2bf(f);
        }
      }
    }
  }
}

// ---------------- fused MLP1+GCN1 GEMM: A=x_bf [M,512], Bt=[768,512] ----------------
__global__ __launch_bounds__(256)
void gemm_fused(const unsigned short* __restrict__ A,
                const unsigned short* __restrict__ Bt,
                const float* __restrict__ mb1,
                unsigned short* __restrict__ h1,
                unsigned short* __restrict__ g1,
                int M)
{
  const int nwg  = gridDim.x * gridDim.y;
  const int wgid = xcd_swizzle(blockIdx.y * gridDim.x + blockIdx.x, nwg);
  const int bnt  = wgid % gridDim.x;
  const int bn   = bnt << 7;
  const int bm   = (wgid / gridDim.x) << 7;

  GEMM_BODY(A, 512, Bt, 512, M, 768, 512, bm, bn)

  const int q   = lane >> 4;
  const int r15 = lane & 15;
  if (bnt < 4) {   // h1: bias + relu
#pragma unroll
    for (int m = 0; m < 4; ++m) {
#pragma unroll
      for (int n = 0; n < 4; ++n) {
        const int gc = bn + wn + n * 16 + r15;
        const float b = mb1[gc];
#pragma unroll
        for (int i = 0; i < 4; ++i) {
          const int gr = bm + wm + m * 16 + q * 4 + i;
          if (gr < M) h1[(size_t)gr * 512 + gc] = f2bf(fmaxf(acc[m][n][i] + b, 0.f));
        }
      }
    }
  } else {         // g1: plain
#pragma unroll
    for (int m = 0; m < 4; ++m) {
#pragma unroll
      for (int n = 0; n < 4; ++n) {
        const int gc = bn - 512 + wn + n * 16 + r15;
#pragma unroll
        for (int i = 0; i < 4; ++i) {
          const int gr = bm + wm + m * 16 + q * 4 + i;
          if (gr < M) g1[(size_t)gr * 256 + gc] = f2bf(acc[m][n][i]);
        }
      }
    }
  }
}

// ---------------- fused MLP2+logits: A=h1 [M,512], Bt=mw2t [64,512] ----------------
// 128x64 tile, 4 waves x 32 rows, acc[2][4]. Epilogue computes h2=relu(.+mb2) in f32,
// then L = h2 @ mw3p (+mb3) via 16-lane shfl reduce, then T = L @ relu(2*P).
// h2 is never materialized; replaces the generic N=64 GEMM (half-wasted tile) + logits.
__global__ __launch_bounds__(256)
void mlp2_logits_kernel(const unsigned short* __restrict__ A,
                        const unsigned short* __restrict__ Bt,
                        const float* __restrict__ mb2,
                        const float* __restrict__ mw3p,
                        const float* __restrict__ mb3,
                        const float* __restrict__ par,
                        float* __restrict__ Lg, float* __restrict__ Tg,
                        int M)
{
  __shared__ unsigned short ldsA[2][128 * 64];
  __shared__ unsigned short ldsB[2][64 * 64];
  __shared__ float Psh[64];
  const int tid  = threadIdx.x;
  const int lane = tid & 63;
  const int wid  = tid >> 6;
  const int bm   = blockIdx.x << 7;
  f32x4 acc[2][4] = {};
  const int srow8 = lane >> 3;
  const int sks   = (lane & 7) ^ srow8;

  if (tid < 64) {
    int d = tid >> 3, c = tid & 7;
    Psh[tid] = (d < 7 && c < 7) ? fmaxf(2.0f * par[d * 7 + c], 0.f) : 0.f;
  }

#define M2_STAGE(buf, k0)                                                          \
  _Pragma("unroll")                                                                \
  for (int r = 0; r < 4; ++r) {                                                    \
    const int rowA = r * 32 + wid * 8 + srow8;                                     \
    int ga = bm + rowA; ga = ga < M ? ga : M - 1;                                  \
    __builtin_amdgcn_global_load_lds((gas_p)((const char*)A + ((size_t)ga * 512 + (k0)) * 2 + sks * 16), \
                                     (las_p)(ldsA[buf] + rowA * 64), 16, 0, 0);    \
  }                                                                                \
  _Pragma("unroll")                                                                \
  for (int r = 0; r < 2; ++r) {                                                    \
    const int rowB = r * 32 + wid * 8 + srow8;                                     \
    __builtin_amdgcn_global_load_lds((gas_p)((const char*)Bt + ((size_t)rowB * 512 + (k0)) * 2 + sks * 16), \
                                     (las_p)(ldsB[buf] + rowB * 64), 16, 0, 0);    \
  }

  M2_STAGE(0, 0)
  for (int t = 0; t < 8; ++t) {                  // K = 512, BK = 64
    const int cur = t & 1;
    if (t < 7) {
      M2_STAGE(cur ^ 1, (t + 1) << 6)
      asm volatile("s_waitcnt vmcnt(6)" ::: "memory");
    } else {
      asm volatile("s_waitcnt vmcnt(0)" ::: "memory");
    }
    __builtin_amdgcn_s_barrier();
    __builtin_amdgcn_sched_barrier(0);
    const int q   = lane >> 4;
    const int r15 = lane & 15;
#pragma unroll
    for (int kk = 0; kk < 2; ++kk) {
      bf16x8 af[2], bfr[4];
#pragma unroll
      for (int m = 0; m < 2; ++m) {
        const int ra = wid * 32 + m * 16 + r15;
        af[m] = *(const bf16x8*)(ldsA[cur] + ra * 64 + (((kk << 2) + q) ^ (ra & 7)) * 8);
      }
#pragma unroll
      for (int n = 0; n < 4; ++n) {
        const int rb = n * 16 + r15;
        bfr[n] = *(const bf16x8*)(ldsB[cur] + rb * 64 + (((kk << 2) + q) ^ (rb & 7)) * 8);
      }
#pragma unroll
      for (int m = 0; m < 2; ++m)
#pragma unroll
        for (int n = 0; n < 4; ++n)
          acc[m][n] = __builtin_amdgcn_mfma_f32_16x16x32_bf16(af[m], bfr[n], acc[m][n], 0, 0, 0);
    }
    __builtin_amdgcn_sched_barrier(0);
    __builtin_amdgcn_s_barrier();
  }

  // epilogue: per lane 4 cols (n*16+r15); reduce L across the 16 r15-lanes per row
  const int q   = lane >> 4;
  const int r15 = lane & 15;
#pragma unroll
  for (int m = 0; m < 2; ++m) {
#pragma unroll
    for (int i = 0; i < 4; ++i) {
      f32x4 Llo = {0,0,0,0}, Lhi = {0,0,0,0};
#pragma unroll
      for (int n = 0; n < 4; ++n) {
        const int colB = n * 16 + r15;
        float h2v = fmaxf(acc[m][n][i] + mb2[colB], 0.f);
        Llo += h2v * *(const f32x4*)(mw3p + colB * 8);
        Lhi += h2v * *(const f32x4*)(mw3p + colB * 8 + 4);
      }
#pragma unroll
      for (int off = 1; off < 16; off <<= 1) {
        Llo[0] += __shfl_xor(Llo[0], off); Llo[1] += __shfl_xor(Llo[1], off);
        Llo[2] += __shfl_xor(Llo[2], off); Llo[3] += __shfl_xor(Llo[3], off);
        Lhi[0] += __shfl_xor(Lhi[0], off); Lhi[1] += __shfl_xor(Lhi[1], off);
        Lhi[2] += __shfl_xor(Lhi[2], off); Lhi[3] += __shfl_xor(Lhi[3], off);
      }
      if (r15 == 0) {
        const int grow = bm + wid * 32 + m * 16 + q * 4 + i;
        if (grow < M) {
          float Ls[8];
          Ls[0] = Llo[0] + mb3[0]; Ls[1] = Llo[1] + mb3[1];
          Ls[2] = Llo[2] + mb3[2]; Ls[3] = Llo[3] + mb3[3];
          Ls[4] = Lhi[0] + mb3[4]; Ls[5] = Lhi[1] + mb3[5];
          Ls[6] = Lhi[2] + mb3[6]; Ls[7] = 0.f;
          f32x4 T0 = {0,0,0,0}, T1 = {0,0,0,0};
#pragma unroll
          for (int d = 0; d < 7; ++d) {
            T0 += Ls[d] * *(const f32x4*)&Psh[d * 8];
            T1 += Ls[d] * *(const f32x4*)&Psh[d * 8 + 4];
          }
          f32x4 o0 = {Ls[0], Ls[1], Ls[2], Ls[3]};
          f32x4 o1 = {Ls[4], Ls[5], Ls[6], 0.f};
          *(f32x4*)(Lg + (size_t)grow * 8)     = o0;
          *(f32x4*)(Lg + (size_t)grow * 8 + 4) = o1;
          *(f32x4*)(Tg + (size_t)grow * 8)     = T0;
          *(f32x4*)(Tg + (size_t)grow * 8 + 4) = T1;
        }
      }
    }
  }
}

// ---------------- edge pass 1: 4 edges/thread; ew + cnt atomic (rank captured) ----
__global__ __launch_bounds__(256)
void edge1_kernel(const int* __restrict__ row, const int* __restrict__ col,
                  const float* __restrict__ Lg, const float* __restrict__ Tg,
                  float* __restrict__ ew_raw, int* __restrict__ cnt,
                  unsigned short* __restrict__ rk, double* __restrict__ part)
{
  __shared__ double shs[4], shs2[4];
  const int base = blockIdx.x * 1024 + threadIdx.x;
  double s = 0.0, s2 = 0.0;
  int idx[4]; bool ok[4];
#pragma unroll
  for (int u = 0; u < 4; ++u) { idx[u] = base + u * 256; ok[u] = idx[u] < EE; }
  int r[4], c[4];
#pragma unroll
  for (int u = 0; u < 4; ++u) if (ok[u]) { r[u] = row[idx[u]]; c[u] = col[idx[u]]; }
  float4 A0[4], A1[4], B0[4], B1[4];
#pragma unroll
  for (int u = 0; u < 4; ++u) if (ok[u]) {
    A0[u] = *(const float4*)(Lg + (size_t)r[u] * 8);
    A1[u] = *(const float4*)(Lg + (size_t)r[u] * 8 + 4);
    B0[u] = *(const float4*)(Tg + (size_t)c[u] * 8);
    B1[u] = *(const float4*)(Tg + (size_t)c[u] * 8 + 4);
  }
#pragma unroll
  for (int u = 0; u < 4; ++u) if (ok[u]) {
    float v = A0[u].x*B0[u].x + A0[u].y*B0[u].y + A0[u].z*B0[u].z + A0[u].w*B0[u].w
            + A1[u].x*B1[u].x + A1[u].y*B1[u].y + A1[u].z*B1[u].z + A1[u].w*B1[u].w;
    ew_raw[idx[u]] = v;
    int p = atomicAdd(&cnt[c[u]], 1);
    rk[idx[u]] = (unsigned short)p;
    s += (double)v; s2 += (double)v * (double)v;
  }
  for (int off = 32; off; off >>= 1) {
    s  += __shfl_down(s, off);
    s2 += __shfl_down(s2, off);
  }
  int wv = threadIdx.x >> 6;
  if ((threadIdx.x & 63) == 0) { shs[wv] = s; shs2[wv] = s2; }
  __syncthreads();
  if (threadIdx.x == 0) {
    part[blockIdx.x]         = shs[0] + shs[1] + shs[2] + shs[3];
    part[NB_E1 + blockIdx.x] = shs2[0] + shs2[1] + shs2[2] + shs2[3];
  }
}

// ---------------- reduce edge1 partials -> red ----------------
__global__ __launch_bounds__(1024)
void redpart_kernel(const double* __restrict__ part, double* __restrict__ red)
{
  __shared__ double sh[16][2];
  int tid = threadIdx.x;
  double s = 0.0, s2 = 0.0;
  for (int i = tid; i < NB_E1; i += 1024) {
    s  += part[i];
    s2 += part[NB_E1 + i];
  }
  for (int off = 32; off; off >>= 1) {
    s  += __shfl_down(s, off);
    s2 += __shfl_down(s2, off);
  }
  if ((tid & 63) == 0) { sh[tid >> 6][0] = s; sh[tid >> 6][1] = s2; }
  __syncthreads();
  if (tid == 0) {
    double a = 0.0, b = 0.0;
    for (int i = 0; i < 16; ++i) { a += sh[i][0]; b += sh[i][1]; }
    red[0] = a; red[1] = b;
  }
}

// ---------------- edge pass 2: standardize + CSR place at rowptr[c]+rk[e] (NO atomics) ----
__global__ __launch_bounds__(256)
void edge2_kernel(const int* __restrict__ row, const int* __restrict__ col,
                  const float* __restrict__ ew_raw, const unsigned short* __restrict__ rk,
                  const double* __restrict__ red, const int* __restrict__ rowptr,
                  int2* __restrict__ csr_sw)
{
  int e = blockIdx.x * 256 + threadIdx.x;
  if (e >= EE) return;
  double mean = red[0] / (double)EE;
  double var  = (red[1] - (double)EE * mean * mean) / (double)(EE - 1);
  double scl  = sqrt(1e-4 / var);
  float v = (float)(((double)ew_raw[e] - mean) * scl) + 1.0f;
  int r = row[e], c = col[e];
  int2 sw; sw.x = r; sw.y = __float_as_int(v);
  csr_sw[rowptr[c] + (int)rk[e]] = sw;
}

// ---------------- deg from CSR rows (no atomics) + dinv ----------------
__global__ __launch_bounds__(256)
void degdinv_kernel(const int* __restrict__ rowptr, const int2* __restrict__ csr_sw,
                    float* __restrict__ dinv)
{
  int n = blockIdx.x * 256 + threadIdx.x;
  if (n >= NN) return;
  int s = rowptr[n], e = rowptr[n + 1];
  float deg = 0.f;
  for (int i = s; i < e; ++i) deg += __int_as_float(csr_sw[i].y);
  float d = deg + 1.0f;   // + self-loop weight 1
  dinv[n] = d > 0.f ? 1.0f / sqrtf(fmaxf(d, 1e-12f)) : 0.f;
}

// ---------------- scale csr weights by dinv[src] (coalesced) ----------------
__global__ __launch_bounds__(256)
void scale_csr_kernel(int2* __restrict__ csr_sw, const float* __restrict__ dinv)
{
  int i = blockIdx.x * 256 + threadIdx.x;
  if (i >= EE) return;
  int2 sw = csr_sw[i];
  sw.y = __float_as_int(__int_as_float(sw.y) * dinv[sw.x]);
  csr_sw[i] = sw;
}

// ---------------- parallel 3-stage exclusive scan of cnt -> rowptr ----------------
__global__ __launch_bounds__(256)
void scan1_kernel(const int* __restrict__ cnt, int* __restrict__ bsum)
{
  __shared__ int sh[4];
  int i = blockIdx.x * 256 + threadIdx.x;
  int v = (i < NN) ? cnt[i] : 0;
  for (int off = 32; off; off >>= 1) v += __shfl_down(v, off);
  if ((threadIdx.x & 63) == 0) sh[threadIdx.x >> 6] = v;
  __syncthreads();
  if (threadIdx.x == 0) bsum[blockIdx.x] = sh[0] + sh[1] + sh[2] + sh[3];
}

__global__ __launch_bounds__(256)
void scan2_kernel(int* __restrict__ bsum)
{
  __shared__ int sh[256];
  int tid = threadIdx.x;
  int v = (tid < NB_SCAN) ? bsum[tid] : 0;
  sh[tid] = v;
  __syncthreads();
  for (int off = 1; off < 256; off <<= 1) {
    int t = (tid >= off) ? sh[tid - off] : 0;
    __syncthreads();
    sh[tid] += t;
    __syncthreads();
  }
  if (tid < NB_SCAN) bsum[tid] = sh[tid] - v;   // exclusive
}

__global__ __launch_bounds__(256)
void scan3_kernel(const int* __restrict__ cnt, const int* __restrict__ bsum,
                  int* __restrict__ rowptr)
{
  __shared__ int sh[256];
  int tid = threadIdx.x;
  int i = blockIdx.x * 256 + tid;
  int v = (i < NN) ? cnt[i] : 0;
  sh[tid] = v;
  __syncthreads();
  for (int off = 1; off < 256; off <<= 1) {
    int t = (tid >= off) ? sh[tid - off] : 0;
    __syncthreads();
    sh[tid] += t;
    __syncthreads();
  }
  if (i < NN) rowptr[i + 1] = bsum[blockIdx.x] + sh[tid];
  if (i == 0) rowptr[0] = 0;
}

// ---------------- dim-256 aggregation: one node per HALF-WAVE, persistent grid ----
#define AGG_ACC(sw_, v_)                                                     \
  {                                                                          \
    float w_ = __int_as_float((sw_).y);                                      \
    a0 += w_ * bf2f((v_)[0]); a1 += w_ * bf2f((v_)[1]);                      \
    a2 += w_ * bf2f((v_)[2]); a3 += w_ * bf2f((v_)[3]);                      \
    a4 += w_ * bf2f((v_)[4]); a5 += w_ * bf2f((v_)[5]);                      \
    a6 += w_ * bf2f((v_)[6]); a7 += w_ * bf2f((v_)[7]);                      \
  }

template<int MODE>
__global__ __launch_bounds__(256)
void agg256_kernel(const int* __restrict__ rowptr, const int2* __restrict__ csr_sw,
                   const unsigned short* __restrict__ gsrc,
                   const float* __restrict__ dinv, const float* __restrict__ bias,
                   const unsigned short* __restrict__ h0in,
                   unsigned short* __restrict__ h0out,
                   unsigned short* __restrict__ xout,
                   const float* __restrict__ w3p, float* __restrict__ y3)
{
  const int tid = threadIdx.x;
  const int hw  = tid >> 5;          // half-wave 0..7
  const int l5  = tid & 31;
  const size_t colbase = (size_t)(l5 << 3);
  const int stride = (int)gridDim.x * 8;

  for (int n = blockIdx.x * 8 + hw; n < NN; n += stride) {
    const int dbase = l5 << 3;
    const float dn = dinv[n];
    u16x8 sv = *(const u16x8*)(gsrc + (size_t)n * 256 + dbase);
    float4 b0 = *(const float4*)(bias + dbase);
    float4 b1 = *(const float4*)(bias + dbase + 4);
    float a0=0,a1=0,a2=0,a3=0,a4=0,a5=0,a6=0,a7=0;
    const int s = rowptr[n], e = rowptr[n + 1];
    int i = s;
    for (; i + 7 < e; i += 8) {               // 8 gathers in flight
      int2 sw[8];
#pragma unroll
      for (int u = 0; u < 8; ++u) sw[u] = csr_sw[i + u];
      u16x8 v[8];
#pragma unroll
      for (int u = 0; u < 8; ++u) v[u] = *(const u16x8*)(gsrc + (size_t)sw[u].x * 256 + colbase);
#pragma unroll
      for (int u = 0; u < 8; ++u) AGG_ACC(sw[u], v[u])
    }
    for (; i + 3 < e; i += 4) {
      int2 sw[4];
#pragma unroll
      for (int u = 0; u < 4; ++u) sw[u] = csr_sw[i + u];
      u16x8 v[4];
#pragma unroll
      for (int u = 0; u < 4; ++u) v[u] = *(const u16x8*)(gsrc + (size_t)sw[u].x * 256 + colbase);
#pragma unroll
      for (int u = 0; u < 4; ++u) AGG_ACC(sw[u], v[u])
    }
    for (; i < e; ++i) {
      int2 sw = csr_sw[i];
      u16x8 v = *(const u16x8*)(gsrc + (size_t)sw.x * 256 + colbase);
      AGG_ACC(sw, v)
    }
    const float wd = dn * dn;
    float f0 = dn * a0 + wd * bf2f(sv[0]) + b0.x;
    float f1 = dn * a1 + wd * bf2f(sv[1]) + b0.y;
    float f2 = dn * a2 + wd * bf2f(sv[2]) + b0.z;
    float f3 = dn * a3 + wd * bf2f(sv[3]) + b0.w;
    float f4 = dn * a4 + wd * bf2f(sv[4]) + b1.x;
    float f5 = dn * a5 + wd * bf2f(sv[5]) + b1.y;
    float f6 = dn * a6 + wd * bf2f(sv[6]) + b1.z;
    float f7 = dn * a7 + wd * bf2f(sv[7]) + b1.w;
    const size_t o = (size_t)n * 256 + dbase;
    if (MODE == 0) {
      u16x8 h;
      h[0] = f2bf(f0); h[1] = f2bf(f1); h[2] = f2bf(f2); h[3] = f2bf(f3);
      h[4] = f2bf(f4); h[5] = f2bf(f5); h[6] = f2bf(f6); h[7] = f2bf(f7);
      *(u16x8*)(h0out + o) = h;
      u16x8 xo;
      xo[0] = f2bf(fmaxf(f0, 0.f)); xo[1] = f2bf(fmaxf(f1, 0.f));
      xo[2] = f2bf(fmaxf(f2, 0.f)); xo[3] = f2bf(fmaxf(f3, 0.f));
      xo[4] = f2bf(fmaxf(f4, 0.f)); xo[5] = f2bf(fmaxf(f5, 0.f));
      xo[6] = f2bf(fmaxf(f6, 0.f)); xo[7] = f2bf(fmaxf(f7, 0.f));
      *(u16x8*)(xout + o) = xo;
    } else {
      u16x8 h = *(const u16x8*)(h0in + o);
      float xv0 = bf2f(f2bf(fmaxf(f0, 0.f) + bf2f(h[0])));
      float xv1 = bf2f(f2bf(fmaxf(f1, 0.f) + bf2f(h[1])));
      float xv2 = bf2f(f2bf(fmaxf(f2, 0.f) + bf2f(h[2])));
      float xv3 = bf2f(f2bf(fmaxf(f3, 0.f) + bf2f(h[3])));
      float xv4 = bf2f(f2bf(fmaxf(f4, 0.f) + bf2f(h[4])));
      float xv5 = bf2f(f2bf(fmaxf(f5, 0.f) + bf2f(h[5])));
      float xv6 = bf2f(f2bf(fmaxf(f6, 0.f) + bf2f(h[6])));
      float xv7 = bf2f(f2bf(fmaxf(f7, 0.f) + bf2f(h[7])));
      const float* w3r = w3p + (size_t)dbase * 8;
      f32x4 p0 = {0,0,0,0}, p1 = {0,0,0,0};
      p0 += xv0 * *(const f32x4*)(w3r +  0); p1 += xv0 * *(const f32x4*)(w3r +  4);
      p0 += xv1 * *(const f32x4*)(w3r +  8); p1 += xv1 * *(const f32x4*)(w3r + 12);
      p0 += xv2 * *(const f32x4*)(w3r + 16); p1 += xv2 * *(const f32x4*)(w3r + 20);
      p0 += xv3 * *(const f32x4*)(w3r + 24); p1 += xv3 * *(const f32x4*)(w3r + 28);
      p0 += xv4 * *(const f32x4*)(w3r + 32); p1 += xv4 * *(const f32x4*)(w3r + 36);
      p0 += xv5 * *(const f32x4*)(w3r + 40); p1 += xv5 * *(const f32x4*)(w3r + 44);
      p0 += xv6 * *(const f32x4*)(w3r + 48); p1 += xv6 * *(const f32x4*)(w3r + 52);
      p0 += xv7 * *(const f32x4*)(w3r + 56); p1 += xv7 * *(const f32x4*)(w3r + 60);
#pragma unroll
      for (int off = 1; off < 32; off <<= 1) {
        p0[0] += __shfl_xor(p0[0], off); p0[1] += __shfl_xor(p0[1], off);
        p0[2] += __shfl_xor(p0[2], off); p0[3] += __shfl_xor(p0[3], off);
        p1[0] += __shfl_xor(p1[0], off); p1[1] += __shfl_xor(p1[1], off);
        p1[2] += __shfl_xor(p1[2], off); p1[3] += __shfl_xor(p1[3], off);
      }
      if (l5 == 0) {
        *(f32x4*)(y3 + (size_t)n * 8)     = p0;
        *(f32x4*)(y3 + (size_t)n * 8 + 4) = p1;
      }
    }
  }
}

// ---------------- dim-7 aggregation: 8 lanes per node, 4-deep ILP ----------------
__global__ __launch_bounds__(256)
void agg7_kernel(const int* __restrict__ rowptr, const int2* __restrict__ csr_sw,
                 const float* __restrict__ y3,
                 const float* __restrict__ dinv, const float* __restrict__ b3,
                 float* __restrict__ out)
{
  int n = blockIdx.x * 32 + (threadIdx.x >> 3);
  if (n >= NN) return;
  int j = threadIdx.x & 7;
  float acc = 0.f;
  int s = rowptr[n], e = rowptr[n + 1];
  int i = s;
  for (; i + 3 < e; i += 4) {
    int2 sw0 = csr_sw[i],     sw1 = csr_sw[i + 1];
    int2 sw2 = csr_sw[i + 2], sw3 = csr_sw[i + 3];
    float v0 = y3[(size_t)sw0.x * 8 + j];
    float v1 = y3[(size_t)sw1.x * 8 + j];
    float v2 = y3[(size_t)sw2.x * 8 + j];
    float v3 = y3[(size_t)sw3.x * 8 + j];
    acc += __int_as_float(sw0.y) * v0 + __int_as_float(sw1.y) * v1
         + __int_as_float(sw2.y) * v2 + __int_as_float(sw3.y) * v3;
  }
  for (; i < e; ++i) {
    int2 sw = csr_sw[i];
    acc += __int_as_float(sw.y) * y3[(size_t)sw.x * 8 + j];
  }
  float dn = dinv[n];
  acc = dn * acc + dn * dn * y3[(size_t)n * 8 + j];
  if (j < 7) out[(size_t)n * 7 + j] = acc + b3[j];
}

// ---------------- host ----------------
extern "C" void kernel_launch(void* const* d_in, const int* in_sizes, int n_in,
                              void* d_out, int out_size, void* d_ws, size_t ws_size,
                              hipStream_t stream)
{
  const float* x   = (const float*)d_in[0];
  const int*   ei  = (const int*)d_in[1];
  const float* W1  = (const float*)d_in[2];
  const float* b1  = (const float*)d_in[3];
  const float* W2  = (const float*)d_in[4];
  const float* b2  = (const float*)d_in[5];
  const float* W3  = (const float*)d_in[6];
  const float* b3  = (const float*)d_in[7];
  const float* mw1 = (const float*)d_in[8];
  const float* mb1 = (const float*)d_in[9];
  const float* mw2 = (const float*)d_in[10];
  const float* mb2 = (const float*)d_in[11];
  const float* mw3 = (const float*)d_in[12];
  const float* mb3 = (const float*)d_in[13];
  const float* par = (const float*)d_in[14];
  const int* row = ei;
  const int* col = ei + EE;
  float* out = (float*)d_out;

  char* ws = (char*)d_ws;
  unsigned short* x_bf  = (unsigned short*)(ws + O_XBF);
  unsigned short* h0    = (unsigned short*)(ws + O_XBF);   // bf16, alias (x_bf dead after fused GEMM)
  unsigned short* h1_bf = (unsigned short*)(ws + O_H1);
  unsigned short* g2_bf = (unsigned short*)(ws + O_H1);    // reuse (h1 dead)
  unsigned short* g1_bf = (unsigned short*)(ws + O_G1);
  unsigned short* x1_bf = (unsigned short*)(ws + O_X1);
  float* Lg      = (float*)(ws + O_LG);
  float* Tg      = (float*)(ws + O_TG);
  float* ew_raw  = (float*)(ws + O_EWR);
  float* y3      = (float*)(ws + O_EWR);                   // reuse (ew_raw dead after edge2)
  float* w3p     = (float*)(ws + O_W3P);
  unsigned short* rk = (unsigned short*)(ws + O_RK);
  float* mw3p    = (float*)(ws + O_MW3P);
  int2*  csr_sw  = (int2*)(ws + O_CSR);
  double* part   = (double*)(ws + O_CSR);                  // alias: consumed before edge2 fills csr
  unsigned short* mw1t = (unsigned short*)(ws + O_MW1T);   // fused Bt = [mw1t; w1t], 768 rows
  unsigned short* w1t  = (unsigned short*)(ws + O_W1T);
  unsigned short* w2t  = (unsigned short*)(ws + O_W2T);
  unsigned short* mw2t = (unsigned short*)(ws + O_MW2T);
  int*    cnt    = (int*)(ws + O_CNT);
  double* red    = (double*)(ws + O_RED);
  int*    rowptr = (int*)(ws + O_RPT);
  float*  dinv   = (float*)(ws + O_DINV);
  int*    bsum   = (int*)(ws + O_BSUM);

  // zero: cnt
  hipMemsetAsync(ws + O_CNT, 0, 200192, stream);

  // fp32 -> bf16 conversions (+ padded W3/mw3)
  conv_f2bf4<<<25000, 256, 0, stream>>>(x, x_bf, NN * 512 / 4);
  conv_weights<<<1930, 256, 0, stream>>>(mw1, W1, W2, mw2, W3, mw3, mw1t, w1t, w2t, mw2t, w3p, mw3p);

  // fused MLP1 + GCN1 GEMM
  gemm_fused<<<dim3(6, 391), 256, 0, stream>>>(x_bf, mw1t, mb1, h1_bf, g1_bf, NN);
  // fused MLP2 + logits (h2 never materialized)
  mlp2_logits_kernel<<<391, 256, 0, stream>>>(h1_bf, mw2t, mb2, mw3p, mb3, par, Lg, Tg, NN);

  // edge weights + CSR (rank captured in edge1's cnt atomic; edge2 is atomic-free)
  edge1_kernel<<<NB_E1, 256, 0, stream>>>(row, col, Lg, Tg, ew_raw, cnt, rk, part);
  redpart_kernel<<<1, 1024, 0, stream>>>(part, red);
  scan1_kernel<<<NB_SCAN, 256, 0, stream>>>(cnt, bsum);
  scan2_kernel<<<1, 256, 0, stream>>>(bsum);
  scan3_kernel<<<NB_SCAN, 256, 0, stream>>>(cnt, bsum, rowptr);
  edge2_kernel<<<NB_EDGE, 256, 0, stream>>>(row, col, ew_raw, rk, red, rowptr, csr_sw);
  degdinv_kernel<<<196, 256, 0, stream>>>(rowptr, csr_sw, dinv);
  scale_csr_kernel<<<NB_EDGE, 256, 0, stream>>>(csr_sw, dinv);

  // GCN layer 0 aggregation (persistent grid)
  agg256_kernel<0><<<1536, 256, 0, stream>>>(rowptr, csr_sw, g1_bf, dinv, b1, nullptr, h0, x1_bf, nullptr, nullptr);
  // GCN layer 1 (+residual h0), fused with W3 gemv -> y3
  gemm_bf16<false, false><<<dim3(2, 391), 256, 0, stream>>>(x1_bf, 256, w2t, nullptr, g2_bf, 256, NN, 256, 256);
  agg256_kernel<1><<<1536, 256, 0, stream>>>(rowptr, csr_sw, g2_bf, dinv, b2, h0, nullptr, nullptr, w3p, y3);
  // final dim-7 aggregation
  agg7_kernel<<<1563, 256, 0, stream>>>(rowptr, csr_sw, y3, dinv, b3, out);
}